// Round 2
// baseline (601.947 us; speedup 1.0000x reference)
//
#include <hip/hip_runtime.h>

#define B_ 128
#define F_ 128
#define T_ 512
#define TS 64
#define DIAG_N 1024   // padded diagonal count (1023 used)

// Large finite sentinel instead of INF: survives fast-math, never overflows.
#define BIGV 1e30f

// ---------------------------------------------------------------------------
// Kernel 1: cost[b][i][j] = sqrt(max(||x_i||^2 + ||y_j||^2 - 2 x_i.y_j, 0))
// written DIAGONAL-MAJOR: costD[b][i+j][j].  Tiled 64x64, f32 VALU GEMM.
// grid = (T/64, T/64, Bg), block = 256. Epilogue transposes the 64x64 tile
// through LDS (stride 68 -> 2-way banks on anti-diagonal reads) so global
// stores are coalesced along each diagonal row.
// ---------------------------------------------------------------------------
__global__ __launch_bounds__(256) void dtw_cost_kernel(
    const float* __restrict__ x, const float* __restrict__ y,
    float* __restrict__ costD, int b0)
{
    const int tj  = blockIdx.x;      // column tile 0..7
    const int ti  = blockIdx.y;      // row tile 0..7
    const int bl  = blockIdx.z;      // local batch index within group
    const int b   = b0 + bl;
    const int tid = threadIdx.x;
    const int gi0 = ti * TS;
    const int gj0 = tj * TS;

    __shared__ __align__(16) float Xs[F_][TS];
    __shared__ __align__(16) float Ys[F_][TS];
    __shared__ float x2s[TS];
    __shared__ float y2s[TS];

    const float* xb = x + (size_t)b * F_ * T_;
    const float* yb = y + (size_t)b * F_ * T_;

    // stage: 128 f-rows x 64 floats each; 256 threads -> 16 f-rows per pass.
    const int fr = tid >> 4;         // 0..15
    const int q  = (tid & 15) * 4;   // 0,4,...,60
#pragma unroll
    for (int p = 0; p < 8; ++p) {
        const int f = p * 16 + fr;
        *(float4*)(&Xs[f][q]) = *(const float4*)(xb + (size_t)f * T_ + gi0 + q);
        *(float4*)(&Ys[f][q]) = *(const float4*)(yb + (size_t)f * T_ + gj0 + q);
    }
    __syncthreads();

    // column squared-norms
    if (tid < 64) {
        float s = 0.f;
#pragma unroll
        for (int f = 0; f < F_; ++f) { const float v = Xs[f][tid]; s += v * v; }
        x2s[tid] = s;
    } else if (tid < 128) {
        const int c = tid - 64;
        float s = 0.f;
#pragma unroll
        for (int f = 0; f < F_; ++f) { const float v = Ys[f][c]; s += v * v; }
        y2s[c] = s;
    }
    __syncthreads();

    // 4x4 micro-tile per thread
    const int tr = tid >> 4;   // 0..15
    const int tc = tid & 15;   // 0..15
    float acc[4][4] = {};
#pragma unroll 8
    for (int k = 0; k < F_; ++k) {
        const float4 xa = *(const float4*)(&Xs[k][tr * 4]);
        const float4 ya = *(const float4*)(&Ys[k][tc * 4]);
        const float xv[4] = {xa.x, xa.y, xa.z, xa.w};
        const float yv[4] = {ya.x, ya.y, ya.z, ya.w};
#pragma unroll
        for (int r = 0; r < 4; ++r)
#pragma unroll
            for (int c = 0; c < 4; ++c)
                acc[r][c] = fmaf(xv[r], yv[c], acc[r][c]);
    }

    // finalize cost values in registers
    float4 ov[4];
#pragma unroll
    for (int r = 0; r < 4; ++r) {
        const float x2v = x2s[tr * 4 + r];
        ov[r].x = sqrtf(fmaxf(x2v + y2s[tc * 4 + 0] - 2.f * acc[r][0], 0.f));
        ov[r].y = sqrtf(fmaxf(x2v + y2s[tc * 4 + 1] - 2.f * acc[r][1], 0.f));
        ov[r].z = sqrtf(fmaxf(x2v + y2s[tc * 4 + 2] - 2.f * acc[r][2], 0.f));
        ov[r].w = sqrtf(fmaxf(x2v + y2s[tc * 4 + 3] - 2.f * acc[r][3], 0.f));
    }

    // transpose tile through LDS (reuse Xs storage; 64 x 68 stride)
    __syncthreads();                       // all GEMM-phase LDS reads done
    float* Ts = &Xs[0][0];                 // 64*68 = 4352 floats <= 8192
#pragma unroll
    for (int r = 0; r < 4; ++r)
        *(float4*)(&Ts[(tr * 4 + r) * 68 + tc * 4]) = ov[r];
    __syncthreads();

    // diagonal-coalesced write-out: diag tloc has cells (r = tloc-c, c)
    const int w    = tid >> 6;             // wave 0..3
    const int lane = tid & 63;
    float* outD = costD + (size_t)bl * (DIAG_N * (size_t)T_);
    const int tbase = gi0 + gj0;
#pragma unroll 4
    for (int g = 0; g < 32; ++g) {
        const int tloc = g * 4 + w;        // 0..127
        if (tloc <= 126) {
            const int c0 = tloc > 63 ? tloc - 63 : 0;
            const int c1 = tloc < 63 ? tloc : 63;
            const int c  = c0 + lane;
            if (c <= c1)
                outD[(size_t)(tbase + tloc) * T_ + gj0 + c] =
                    Ts[68 * (tloc - c) + c];
        }
    }
}

// ---------------------------------------------------------------------------
// Kernel 2: anti-diagonal DTW DP. One 64-lane wave per batch, lane L owns
// columns j = 8L..8L+7. Tick t computes all cells with i+j == t:
//   dp[i][j] = c[i][j] + min(dp[i-1][j], dp[i][j-1], dp[i-1][j-1])
// v1 = values on diag t-1, v2 = diag t-2 (per slot). Only slot 0 needs the
// neighbor lane's slot-7 values (2 shfl_up per tick). Invalid slots carry
// ~1e30 lattice values; junk cost loads for invalid cells are laundered by
// the fminf chain (first valid tick always has a real finite operand).
// Loads: 2 predicated coalesced float4 per lane per tick, pipelined 8 deep.
// ---------------------------------------------------------------------------
__global__ __launch_bounds__(64) void dtw_dp_diag(
    const float* __restrict__ costD, float* __restrict__ out, int b0)
{
    const int bl = blockIdx.x;
    const int L  = threadIdx.x;
    const float* base = costD + (size_t)bl * (DIAG_N * (size_t)T_) + 8 * L;

    float v1_0 = BIGV, v1_1 = BIGV, v1_2 = BIGV, v1_3 = BIGV,
          v1_4 = BIGV, v1_5 = BIGV, v1_6 = BIGV, v1_7 = BIGV;
    float v2_0 = BIGV, v2_1 = BIGV, v2_2 = BIGV, v2_3 = BIGV,
          v2_4 = BIGV, v2_5 = BIGV, v2_6 = BIGV, v2_7 = BIGV;

    float4 A0 = {0,0,0,0}, B0 = {0,0,0,0}, A1 = {0,0,0,0}, B1 = {0,0,0,0},
           A2 = {0,0,0,0}, B2 = {0,0,0,0}, A3 = {0,0,0,0}, B3 = {0,0,0,0},
           A4 = {0,0,0,0}, B4 = {0,0,0,0}, A5 = {0,0,0,0}, B5 = {0,0,0,0},
           A6 = {0,0,0,0}, B6 = {0,0,0,0}, A7 = {0,0,0,0}, B7 = {0,0,0,0};

#define LOADT(tt, Av, Bv) do {                                              \
    const int t_  = (tt);                                                   \
    const int tlo = (t_ > (T_ - 1)) ? (t_ - (T_ - 1)) : 0;                  \
    const int thi = (t_ < (T_ - 1)) ? t_ : (T_ - 1);                        \
    const float* p_ = base + (size_t)t_ * T_;                               \
    if (8 * L + 3 >= tlo && 8 * L     <= thi) Av = *(const float4*)(p_);    \
    if (8 * L + 7 >= tlo && 8 * L + 4 <= thi) Bv = *(const float4*)(p_ + 4);\
} while (0)

#define STEP(tt, Av, Bv) do {                                               \
    const int t_ = (tt);                                                    \
    float s1 = __shfl_up(v1_7, 1);                                          \
    float s2 = __shfl_up(v2_7, 1);                                          \
    if (L == 0) { s1 = BIGV; s2 = (t_ == 0) ? 0.f : BIGV; }                 \
    const float n0 = Av.x + fminf(fminf(v1_0, s1),   s2);                   \
    const float n1 = Av.y + fminf(fminf(v1_1, v1_0), v2_0);                 \
    const float n2 = Av.z + fminf(fminf(v1_2, v1_1), v2_1);                 \
    const float n3 = Av.w + fminf(fminf(v1_3, v1_2), v2_2);                 \
    const float n4 = Bv.x + fminf(fminf(v1_4, v1_3), v2_3);                 \
    const float n5 = Bv.y + fminf(fminf(v1_5, v1_4), v2_4);                 \
    const float n6 = Bv.z + fminf(fminf(v1_6, v1_5), v2_5);                 \
    const float n7 = Bv.w + fminf(fminf(v1_7, v1_6), v2_6);                 \
    v2_0 = v1_0; v2_1 = v1_1; v2_2 = v1_2; v2_3 = v1_3;                     \
    v2_4 = v1_4; v2_5 = v1_5; v2_6 = v1_6; v2_7 = v1_7;                     \
    v1_0 = n0; v1_1 = n1; v1_2 = n2; v1_3 = n3;                             \
    v1_4 = n4; v1_5 = n5; v1_6 = n6; v1_7 = n7;                             \
} while (0)

    LOADT(0, A0, B0); LOADT(1, A1, B1); LOADT(2, A2, B2); LOADT(3, A3, B3);
    LOADT(4, A4, B4); LOADT(5, A5, B5); LOADT(6, A6, B6); LOADT(7, A7, B7);

    int t = 0;
#pragma unroll 1
    for (int it = 0; it < 127; ++it) {     // 127*8 = 1016 ticks
        STEP(t + 0, A0, B0); LOADT(min(t +  8, 1022), A0, B0);
        STEP(t + 1, A1, B1); LOADT(min(t +  9, 1022), A1, B1);
        STEP(t + 2, A2, B2); LOADT(min(t + 10, 1022), A2, B2);
        STEP(t + 3, A3, B3); LOADT(min(t + 11, 1022), A3, B3);
        STEP(t + 4, A4, B4); LOADT(min(t + 12, 1022), A4, B4);
        STEP(t + 5, A5, B5); LOADT(min(t + 13, 1022), A5, B5);
        STEP(t + 6, A6, B6); LOADT(min(t + 14, 1022), A6, B6);
        STEP(t + 7, A7, B7); LOADT(min(t + 15, 1022), A7, B7);
        t += 8;
    }
    // tail ticks 1016..1022
    STEP(1016, A0, B0); STEP(1017, A1, B1); STEP(1018, A2, B2);
    STEP(1019, A3, B3); STEP(1020, A4, B4); STEP(1021, A5, B5);
    STEP(1022, A6, B6);

    if (L == 63) out[b0 + bl] = v1_7;      // dp[511][511]
#undef LOADT
#undef STEP
}

// ---------------------------------------------------------------------------
extern "C" void kernel_launch(void* const* d_in, const int* in_sizes, int n_in,
                              void* d_out, int out_size, void* d_ws, size_t ws_size,
                              hipStream_t stream)
{
    const float* x = (const float*)d_in[0];
    const float* y = (const float*)d_in[1];
    float* out = (float*)d_out;

    const size_t perb = (size_t)DIAG_N * T_ * sizeof(float);   // 2 MiB / batch
    int Bg = 8;
    for (int g = 128; g >= 8; g >>= 1)
        if (ws_size >= perb * (size_t)g) { Bg = g; break; }

    float* costD = (float*)d_ws;
    for (int b0 = 0; b0 < B_; b0 += Bg) {
        dim3 gc(T_ / TS, T_ / TS, Bg);
        hipLaunchKernelGGL(dtw_cost_kernel, gc, dim3(256), 0, stream,
                           x, y, costD, b0);
        hipLaunchKernelGGL(dtw_dp_diag, dim3(Bg), dim3(64), 0, stream,
                           costD, out, b0);
    }
}

// Round 3
// 356.524 us; speedup vs baseline: 1.6884x; 1.6884x over previous
//
#include <hip/hip_runtime.h>

#define B_ 128
#define F_ 128
#define T_ 512
#define TS 64
#define DIAG_N 1024   // padded diagonal count (1023 used, row 1023 junk-but-allocated)

// Large finite sentinel instead of INF: survives fast-math, never overflows.
#define BIGV 1e30f

// ---------------------------------------------------------------------------
// Kernel 1: cost[b][i][j] = sqrt(max(||x_i||^2 + ||y_j||^2 - 2 x_i.y_j, 0))
// written DIAGONAL-MAJOR: costD[b][i+j][j].  Tiled 64x64, f32 VALU GEMM.
// grid = (T/64, T/64, Bg), block = 256. Epilogue transposes the 64x64 tile
// through LDS (stride 68) so global stores are coalesced along each diagonal.
// (unchanged from round 2 — passing, ~155us)
// ---------------------------------------------------------------------------
__global__ __launch_bounds__(256) void dtw_cost_kernel(
    const float* __restrict__ x, const float* __restrict__ y,
    float* __restrict__ costD, int b0)
{
    const int tj  = blockIdx.x;      // column tile 0..7
    const int ti  = blockIdx.y;      // row tile 0..7
    const int bl  = blockIdx.z;      // local batch index within group
    const int b   = b0 + bl;
    const int tid = threadIdx.x;
    const int gi0 = ti * TS;
    const int gj0 = tj * TS;

    __shared__ __align__(16) float Xs[F_][TS];
    __shared__ __align__(16) float Ys[F_][TS];
    __shared__ float x2s[TS];
    __shared__ float y2s[TS];

    const float* xb = x + (size_t)b * F_ * T_;
    const float* yb = y + (size_t)b * F_ * T_;

    const int fr = tid >> 4;         // 0..15
    const int q  = (tid & 15) * 4;   // 0,4,...,60
#pragma unroll
    for (int p = 0; p < 8; ++p) {
        const int f = p * 16 + fr;
        *(float4*)(&Xs[f][q]) = *(const float4*)(xb + (size_t)f * T_ + gi0 + q);
        *(float4*)(&Ys[f][q]) = *(const float4*)(yb + (size_t)f * T_ + gj0 + q);
    }
    __syncthreads();

    if (tid < 64) {
        float s = 0.f;
#pragma unroll
        for (int f = 0; f < F_; ++f) { const float v = Xs[f][tid]; s += v * v; }
        x2s[tid] = s;
    } else if (tid < 128) {
        const int c = tid - 64;
        float s = 0.f;
#pragma unroll
        for (int f = 0; f < F_; ++f) { const float v = Ys[f][c]; s += v * v; }
        y2s[c] = s;
    }
    __syncthreads();

    const int tr = tid >> 4;   // 0..15
    const int tc = tid & 15;   // 0..15
    float acc[4][4] = {};
#pragma unroll 8
    for (int k = 0; k < F_; ++k) {
        const float4 xa = *(const float4*)(&Xs[k][tr * 4]);
        const float4 ya = *(const float4*)(&Ys[k][tc * 4]);
        const float xv[4] = {xa.x, xa.y, xa.z, xa.w};
        const float yv[4] = {ya.x, ya.y, ya.z, ya.w};
#pragma unroll
        for (int r = 0; r < 4; ++r)
#pragma unroll
            for (int c = 0; c < 4; ++c)
                acc[r][c] = fmaf(xv[r], yv[c], acc[r][c]);
    }

    float4 ov[4];
#pragma unroll
    for (int r = 0; r < 4; ++r) {
        const float x2v = x2s[tr * 4 + r];
        ov[r].x = sqrtf(fmaxf(x2v + y2s[tc * 4 + 0] - 2.f * acc[r][0], 0.f));
        ov[r].y = sqrtf(fmaxf(x2v + y2s[tc * 4 + 1] - 2.f * acc[r][1], 0.f));
        ov[r].z = sqrtf(fmaxf(x2v + y2s[tc * 4 + 2] - 2.f * acc[r][2], 0.f));
        ov[r].w = sqrtf(fmaxf(x2v + y2s[tc * 4 + 3] - 2.f * acc[r][3], 0.f));
    }

    __syncthreads();                       // all GEMM-phase LDS reads done
    float* Ts = &Xs[0][0];                 // 64*68 = 4352 floats
#pragma unroll
    for (int r = 0; r < 4; ++r)
        *(float4*)(&Ts[(tr * 4 + r) * 68 + tc * 4]) = ov[r];
    __syncthreads();

    const int w    = tid >> 6;             // wave 0..3
    const int lane = tid & 63;
    float* outD = costD + (size_t)bl * (DIAG_N * (size_t)T_);
    const int tbase = gi0 + gj0;
#pragma unroll 4
    for (int g = 0; g < 32; ++g) {
        const int tloc = g * 4 + w;        // 0..127
        if (tloc <= 126) {
            const int c0 = tloc > 63 ? tloc - 63 : 0;
            const int c1 = tloc < 63 ? tloc : 63;
            const int c  = c0 + lane;
            if (c <= c1)
                outD[(size_t)(tbase + tloc) * T_ + gj0 + c] =
                    Ts[68 * (tloc - c) + c];
        }
    }
}

// ---------------------------------------------------------------------------
// Kernel 2: anti-diagonal DTW DP. One 64-lane wave per batch, lane L owns
// columns j = 8L..8L+7.
//   dp[i][j] = c[i][j] + min(dp[i-1][j], dp[i][j-1], dp[i-1][j-1])
// UNCONDITIONAL coalesced float4 loads (always in-bounds in the padded
// diagonal buffer; junk cost in never-written cells is laundered by the
// BIGV lattice) so the compiler keeps precise vmcnt tracking — loads are
// issued 8 ticks ahead and must not force per-tick vmcnt(0) drains.
// One bpermute per tick: s2(t) == s1(t-1), carried in a register.
// ---------------------------------------------------------------------------
__global__ __launch_bounds__(64) void dtw_dp_diag(
    const float* __restrict__ costD, float* __restrict__ out, int b0)
{
    const int bl = blockIdx.x;
    const int L  = threadIdx.x;
    const float* base = costD + (size_t)bl * (DIAG_N * (size_t)T_) + 8 * L;

    float v1_0 = BIGV, v1_1 = BIGV, v1_2 = BIGV, v1_3 = BIGV,
          v1_4 = BIGV, v1_5 = BIGV, v1_6 = BIGV, v1_7 = BIGV;
    float v2_0 = BIGV, v2_1 = BIGV, v2_2 = BIGV, v2_3 = BIGV,
          v2_4 = BIGV, v2_5 = BIGV, v2_6 = BIGV;

    // s2 for tick t equals s1 from tick t-1; seed for t=0:
    // shfl_up(v2_7=BIGV) with lane-0 override 0 (dp[-1][-1] = 0 start cell).
    float s2c = (L == 0) ? 0.f : BIGV;

    float4 A0, B0, A1, B1, A2, B2, A3, B3, A4, B4, A5, B5, A6, B6, A7, B7;

#define LOADT(tt, Av, Bv) do {                                              \
    const float* p_ = base + (size_t)(tt) * T_;                             \
    Av = *(const float4*)(p_);                                              \
    Bv = *(const float4*)(p_ + 4);                                          \
} while (0)

#define STEP(Av, Bv) do {                                                   \
    float s1 = __shfl_up(v1_7, 1);                                          \
    if (L == 0) s1 = BIGV;                                                  \
    const float n0 = Av.x + fminf(fminf(v1_0, s1),   s2c);                  \
    const float n1 = Av.y + fminf(fminf(v1_1, v1_0), v2_0);                 \
    const float n2 = Av.z + fminf(fminf(v1_2, v1_1), v2_1);                 \
    const float n3 = Av.w + fminf(fminf(v1_3, v1_2), v2_2);                 \
    const float n4 = Bv.x + fminf(fminf(v1_4, v1_3), v2_3);                 \
    const float n5 = Bv.y + fminf(fminf(v1_5, v1_4), v2_4);                 \
    const float n6 = Bv.z + fminf(fminf(v1_6, v1_5), v2_5);                 \
    const float n7 = Bv.w + fminf(fminf(v1_7, v1_6), v2_6);                 \
    s2c = s1;                                                               \
    v2_0 = v1_0; v2_1 = v1_1; v2_2 = v1_2; v2_3 = v1_3;                     \
    v2_4 = v1_4; v2_5 = v1_5; v2_6 = v1_6;                                  \
    v1_0 = n0; v1_1 = n1; v1_2 = n2; v1_3 = n3;                             \
    v1_4 = n4; v1_5 = n5; v1_6 = n6; v1_7 = n7;                             \
} while (0)

    LOADT(0, A0, B0); LOADT(1, A1, B1); LOADT(2, A2, B2); LOADT(3, A3, B3);
    LOADT(4, A4, B4); LOADT(5, A5, B5); LOADT(6, A6, B6); LOADT(7, A7, B7);

    int t = 0;
#pragma unroll 1
    for (int it = 0; it < 127; ++it) {     // 127*8 = 1016 ticks
        STEP(A0, B0); LOADT(t +  8, A0, B0);
        STEP(A1, B1); LOADT(t +  9, A1, B1);
        STEP(A2, B2); LOADT(t + 10, A2, B2);
        STEP(A3, B3); LOADT(t + 11, A3, B3);
        STEP(A4, B4); LOADT(t + 12, A4, B4);
        STEP(A5, B5); LOADT(t + 13, A5, B5);
        STEP(A6, B6); LOADT(t + 14, A6, B6);
        STEP(A7, B7); LOADT(t + 15, A7, B7);
        t += 8;
    }
    // tail ticks 1016..1022 (A7/B7 holds junk diag 1023, never stepped)
    STEP(A0, B0); STEP(A1, B1); STEP(A2, B2);
    STEP(A3, B3); STEP(A4, B4); STEP(A5, B5);
    STEP(A6, B6);

    if (L == 63) out[b0 + bl] = v1_7;      // dp[511][511]
#undef LOADT
#undef STEP
}

// ---------------------------------------------------------------------------
extern "C" void kernel_launch(void* const* d_in, const int* in_sizes, int n_in,
                              void* d_out, int out_size, void* d_ws, size_t ws_size,
                              hipStream_t stream)
{
    const float* x = (const float*)d_in[0];
    const float* y = (const float*)d_in[1];
    float* out = (float*)d_out;

    const size_t perb = (size_t)DIAG_N * T_ * sizeof(float);   // 2 MiB / batch
    int Bg = 8;
    for (int g = 128; g >= 8; g >>= 1)
        if (ws_size >= perb * (size_t)g) { Bg = g; break; }

    float* costD = (float*)d_ws;
    for (int b0 = 0; b0 < B_; b0 += Bg) {
        dim3 gc(T_ / TS, T_ / TS, Bg);
        hipLaunchKernelGGL(dtw_cost_kernel, gc, dim3(256), 0, stream,
                           x, y, costD, b0);
        hipLaunchKernelGGL(dtw_dp_diag, dim3(Bg), dim3(64), 0, stream,
                           costD, out, b0);
    }
}

// Round 4
// 263.880 us; speedup vs baseline: 2.2811x; 1.3511x over previous
//
#include <hip/hip_runtime.h>
#include <stdint.h>

#define B_ 128
#define F_ 128
#define T_ 512
#define TS 64
#define DIAG_N 1024   // padded diagonal count (1023 used, row 1023 junk-but-allocated)

// Large finite sentinel instead of INF: survives fast-math, never overflows.
#define BIGV 1e30f

typedef __attribute__((ext_vector_type(8))) short  bf16x8;
typedef __attribute__((ext_vector_type(4))) float  f32x4;

static __device__ __forceinline__ unsigned short f32_to_bf16(float f) {
    union { float f; uint32_t u; } v; v.f = f;
    const uint32_t u = v.u + 0x7fffu + ((v.u >> 16) & 1u);   // RNE
    return (unsigned short)(u >> 16);
}

// ---------------------------------------------------------------------------
// Kernel 0: prep. For z=0: x, z=1: y. Per (t-chunk of 64, b, z):
//  - stage 128f x 64t f32 tile in LDS (padded stride 65)
//  - nx[b][t] = sum_f x^2 (f32, exact-input precision)
//  - xt[b][t][f] = bf16(x)  (transposed layout, K-contiguous for MFMA frags)
// ---------------------------------------------------------------------------
__global__ __launch_bounds__(256) void dtw_prep_kernel(
    const float* __restrict__ x, const float* __restrict__ y,
    unsigned short* __restrict__ xt, unsigned short* __restrict__ yt,
    float* __restrict__ nx, float* __restrict__ ny)
{
    const int tch = blockIdx.x;
    const int b   = blockIdx.y;
    const int z   = blockIdx.z;
    const int tid = threadIdx.x;
    const int t0  = tch * 64;

    const float* src      = (z == 0 ? x : y) + (size_t)b * F_ * T_;
    unsigned short* dst   = (z == 0 ? xt : yt) + (size_t)b * T_ * F_;
    float* nd             = (z == 0 ? nx : ny) + (size_t)b * T_;

    __shared__ float S[F_][65];

    const int fr = tid >> 4;
    const int q  = (tid & 15) * 4;
#pragma unroll
    for (int p = 0; p < 8; ++p) {
        const int f = p * 16 + fr;
        const float4 v = *(const float4*)(src + (size_t)f * T_ + t0 + q);
        S[f][q] = v.x; S[f][q + 1] = v.y; S[f][q + 2] = v.z; S[f][q + 3] = v.w;
    }
    __syncthreads();

    if (tid < 64) {
        float s = 0.f;
#pragma unroll
        for (int f = 0; f < F_; ++f) { const float v = S[f][tid]; s = fmaf(v, v, s); }
        nd[t0 + tid] = s;
    }

    // pack bf16 rows: thread -> (t = tid>>2, f-block = (tid&3)*32), 64B store
    const int tl = tid >> 2;
    const int fb = (tid & 3) * 32;
    uint32_t pk[16];
#pragma unroll
    for (int e = 0; e < 16; ++e) {
        const uint32_t lo = f32_to_bf16(S[fb + 2 * e][tl]);
        const uint32_t hi = f32_to_bf16(S[fb + 2 * e + 1][tl]);
        pk[e] = lo | (hi << 16);
    }
    uint32_t* o = (uint32_t*)(dst + (size_t)(t0 + tl) * F_ + fb);
#pragma unroll
    for (int e = 0; e < 16; e += 4)
        *(uint4*)(o + e) = make_uint4(pk[e], pk[e + 1], pk[e + 2], pk[e + 3]);
}

// ---------------------------------------------------------------------------
// Kernel 1: cost[b][i][j] = sqrt(max(nx_i + ny_j - 2 * (x_i . y_j), 0))
// cross-term via mfma_f32_16x16x32_bf16 on XOR-swizzled LDS bf16 tiles.
// Written DIAGONAL-MAJOR costD[b][i+j][j] via the (unchanged) LDS-transpose
// + diagonal-coalesced scatter epilogue.
// grid = (8, 8, Bg), block 256 (4 waves; wave w owns M-strip 16w..16w+15).
// ---------------------------------------------------------------------------
__global__ __launch_bounds__(256) void dtw_cost_kernel(
    const unsigned short* __restrict__ xt, const unsigned short* __restrict__ yt,
    const float* __restrict__ nx, const float* __restrict__ ny,
    float* __restrict__ costD, int b0)
{
    const int tj  = blockIdx.x;
    const int ti  = blockIdx.y;
    const int bl  = blockIdx.z;
    const int b   = b0 + bl;
    const int tid = threadIdx.x;
    const int gi0 = ti * TS;
    const int gj0 = tj * TS;

    __shared__ unsigned short Xs[64 * 128];   // 16 KB, swizzled rows of 256B
    __shared__ unsigned short Ys[64 * 128];   // 16 KB
    __shared__ float x2s[64], y2s[64];

    // stage bf16 tiles (rows: 256B each, 16 lanes x 16B) with XOR swizzle
    {
        const int l16 = tid & 15;
#pragma unroll
        for (int p = 0; p < 4; ++p) {
            const int row = p * 16 + (tid >> 4);
            const uint4 vx = *(const uint4*)(xt + ((size_t)b * T_ + gi0 + row) * F_ + l16 * 8);
            const uint4 vy = *(const uint4*)(yt + ((size_t)b * T_ + gj0 + row) * F_ + l16 * 8);
            const int byt = (row * 256 + l16 * 16) ^ ((row & 7) << 4);
            *(uint4*)((char*)Xs + byt) = vx;
            *(uint4*)((char*)Ys + byt) = vy;
        }
    }
    if (tid < 64)       x2s[tid]      = nx[(size_t)b * T_ + gi0 + tid];
    else if (tid < 128) y2s[tid - 64] = ny[(size_t)b * T_ + gj0 + (tid - 64)];
    __syncthreads();

    const int w    = tid >> 6;
    const int lane = tid & 63;
    const int l15  = lane & 15;
    const int hi   = lane >> 4;

    f32x4 acc[4] = {};
    const int arow = 16 * w + l15;
#pragma unroll
    for (int kb = 0; kb < 4; ++kb) {
        const int koff = kb * 64 + hi * 16;            // byte offset of 8-bf16 frag
        const bf16x8 a = *(const bf16x8*)((const char*)Xs +
                          ((arow * 256 + koff) ^ ((arow & 7) << 4)));
#pragma unroll
        for (int nt = 0; nt < 4; ++nt) {
            const int col = nt * 16 + l15;
            const bf16x8 bb = *(const bf16x8*)((const char*)Ys +
                               ((col * 256 + koff) ^ ((col & 7) << 4)));
            acc[nt] = __builtin_amdgcn_mfma_f32_16x16x32_bf16(a, bb, acc[nt], 0, 0, 0);
        }
    }

    // epilogue: finalize cost, place into Ts[row][col] (stride 68), then
    // diagonal-coalesced scatter (identical to the proven round-2 code).
    __syncthreads();                        // all MFMA LDS reads complete
    float* Ts = (float*)Xs;                 // 64*68*4 = 17408 B overlay
#pragma unroll
    for (int nt = 0; nt < 4; ++nt) {
        const int col = nt * 16 + l15;
        const float y2v = y2s[col];
#pragma unroll
        for (int r = 0; r < 4; ++r) {
            const int row = 16 * w + hi * 4 + r;
            const float c = sqrtf(fmaxf(x2s[row] + y2v - 2.f * acc[nt][r], 0.f));
            Ts[row * 68 + col] = c;
        }
    }
    __syncthreads();

    float* outD = costD + (size_t)bl * (DIAG_N * (size_t)T_);
    const int tbase = gi0 + gj0;
#pragma unroll 4
    for (int g = 0; g < 32; ++g) {
        const int tloc = g * 4 + w;        // 0..127
        if (tloc <= 126) {
            const int c0 = tloc > 63 ? tloc - 63 : 0;
            const int c1 = tloc < 63 ? tloc : 63;
            const int c  = c0 + lane;
            if (c <= c1)
                outD[(size_t)(tbase + tloc) * T_ + gj0 + c] =
                    Ts[68 * (tloc - c) + c];
        }
    }
}

// ---------------------------------------------------------------------------
// Kernel 2: anti-diagonal DTW DP. One 64-lane wave per batch, lane L owns
// columns j = 8L..8L+7. Unconditional coalesced float4 loads (precise vmcnt,
// junk laundered by the BIGV lattice), prefetch pipelined 16 ticks deep.
// ---------------------------------------------------------------------------
__global__ __launch_bounds__(64) void dtw_dp_diag(
    const float* __restrict__ costD, float* __restrict__ out, int b0)
{
    const int bl = blockIdx.x;
    const int L  = threadIdx.x;
    const float* base = costD + (size_t)bl * (DIAG_N * (size_t)T_) + 8 * L;

    float v1_0 = BIGV, v1_1 = BIGV, v1_2 = BIGV, v1_3 = BIGV,
          v1_4 = BIGV, v1_5 = BIGV, v1_6 = BIGV, v1_7 = BIGV;
    float v2_0 = BIGV, v2_1 = BIGV, v2_2 = BIGV, v2_3 = BIGV,
          v2_4 = BIGV, v2_5 = BIGV, v2_6 = BIGV;

    float s2c = (L == 0) ? 0.f : BIGV;

    float4 A0, B0, A1, B1, A2, B2, A3, B3, A4, B4, A5, B5, A6, B6, A7, B7,
           A8, B8, A9, B9, A10, B10, A11, B11, A12, B12, A13, B13, A14, B14,
           A15, B15;

#define LOADT(tt, Av, Bv) do {                                              \
    const float* p_ = base + (size_t)(tt) * T_;                             \
    Av = *(const float4*)(p_);                                              \
    Bv = *(const float4*)(p_ + 4);                                          \
} while (0)

#define STEP(Av, Bv) do {                                                   \
    float s1 = __shfl_up(v1_7, 1);                                          \
    if (L == 0) s1 = BIGV;                                                  \
    const float n0 = Av.x + fminf(fminf(v1_0, s1),   s2c);                  \
    const float n1 = Av.y + fminf(fminf(v1_1, v1_0), v2_0);                 \
    const float n2 = Av.z + fminf(fminf(v1_2, v1_1), v2_1);                 \
    const float n3 = Av.w + fminf(fminf(v1_3, v1_2), v2_2);                 \
    const float n4 = Bv.x + fminf(fminf(v1_4, v1_3), v2_3);                 \
    const float n5 = Bv.y + fminf(fminf(v1_5, v1_4), v2_4);                 \
    const float n6 = Bv.z + fminf(fminf(v1_6, v1_5), v2_5);                 \
    const float n7 = Bv.w + fminf(fminf(v1_7, v1_6), v2_6);                 \
    s2c = s1;                                                               \
    v2_0 = v1_0; v2_1 = v1_1; v2_2 = v1_2; v2_3 = v1_3;                     \
    v2_4 = v1_4; v2_5 = v1_5; v2_6 = v1_6;                                  \
    v1_0 = n0; v1_1 = n1; v1_2 = n2; v1_3 = n3;                             \
    v1_4 = n4; v1_5 = n5; v1_6 = n6; v1_7 = n7;                             \
} while (0)

    LOADT( 0, A0, B0);  LOADT( 1, A1, B1);  LOADT( 2, A2, B2);
    LOADT( 3, A3, B3);  LOADT( 4, A4, B4);  LOADT( 5, A5, B5);
    LOADT( 6, A6, B6);  LOADT( 7, A7, B7);  LOADT( 8, A8, B8);
    LOADT( 9, A9, B9);  LOADT(10, A10, B10); LOADT(11, A11, B11);
    LOADT(12, A12, B12); LOADT(13, A13, B13); LOADT(14, A14, B14);
    LOADT(15, A15, B15);

    int t = 0;
#pragma unroll 1
    for (int it = 0; it < 63; ++it) {      // 63*16 = 1008 ticks
        STEP(A0,  B0);  LOADT(t + 16, A0,  B0);
        STEP(A1,  B1);  LOADT(t + 17, A1,  B1);
        STEP(A2,  B2);  LOADT(t + 18, A2,  B2);
        STEP(A3,  B3);  LOADT(t + 19, A3,  B3);
        STEP(A4,  B4);  LOADT(t + 20, A4,  B4);
        STEP(A5,  B5);  LOADT(t + 21, A5,  B5);
        STEP(A6,  B6);  LOADT(t + 22, A6,  B6);
        STEP(A7,  B7);  LOADT(t + 23, A7,  B7);
        STEP(A8,  B8);  LOADT(t + 24, A8,  B8);
        STEP(A9,  B9);  LOADT(t + 25, A9,  B9);
        STEP(A10, B10); LOADT(t + 26, A10, B10);
        STEP(A11, B11); LOADT(t + 27, A11, B11);
        STEP(A12, B12); LOADT(t + 28, A12, B12);
        STEP(A13, B13); LOADT(t + 29, A13, B13);
        STEP(A14, B14); LOADT(t + 30, A14, B14);
        STEP(A15, B15); LOADT(t + 31, A15, B15);
        t += 16;
    }
    // tail ticks 1008..1022 (A15/B15 holds junk diag 1023, never stepped)
    STEP(A0,  B0);  STEP(A1,  B1);  STEP(A2,  B2);  STEP(A3,  B3);
    STEP(A4,  B4);  STEP(A5,  B5);  STEP(A6,  B6);  STEP(A7,  B7);
    STEP(A8,  B8);  STEP(A9,  B9);  STEP(A10, B10); STEP(A11, B11);
    STEP(A12, B12); STEP(A13, B13); STEP(A14, B14);

    if (L == 63) out[b0 + bl] = v1_7;      // dp[511][511]
#undef LOADT
#undef STEP
}

// ---------------------------------------------------------------------------
extern "C" void kernel_launch(void* const* d_in, const int* in_sizes, int n_in,
                              void* d_out, int out_size, void* d_ws, size_t ws_size,
                              hipStream_t stream)
{
    const float* x = (const float*)d_in[0];
    const float* y = (const float*)d_in[1];
    float* out = (float*)d_out;

    unsigned short* xt = (unsigned short*)d_ws;
    unsigned short* yt = xt + (size_t)B_ * T_ * F_;
    float* nx = (float*)(yt + (size_t)B_ * T_ * F_);
    float* ny = nx + (size_t)B_ * T_;
    float* costD = ny + (size_t)B_ * T_;
    const size_t head = (size_t)((char*)costD - (char*)d_ws);

    const size_t perb = (size_t)DIAG_N * T_ * sizeof(float);   // 2 MiB / batch
    int Bg = 8;
    for (int g = 64; g >= 8; g >>= 1)                          // cap 64: L3-resident dp
        if (ws_size >= head + perb * (size_t)g) { Bg = g; break; }

    hipLaunchKernelGGL(dtw_prep_kernel, dim3(T_ / 64, B_, 2), dim3(256), 0, stream,
                       x, y, xt, yt, nx, ny);

    for (int b0 = 0; b0 < B_; b0 += Bg) {
        dim3 gc(T_ / TS, T_ / TS, Bg);
        hipLaunchKernelGGL(dtw_cost_kernel, gc, dim3(256), 0, stream,
                           xt, yt, nx, ny, costD, b0);
        hipLaunchKernelGGL(dtw_dp_diag, dim3(Bg), dim3(64), 0, stream,
                           costD, out, b0);
    }
}

// Round 5
// 157.828 us; speedup vs baseline: 3.8139x; 1.6719x over previous
//
#include <hip/hip_runtime.h>
#include <stdint.h>

#define B_ 128
#define F_ 128
#define T_ 512
#define TS 64
#define DIAG_N 1024   // padded diagonal count (1023 used, row 1023 junk-but-allocated)

// Large finite sentinel instead of INF: survives fast-math, never overflows.
#define BIGV 1e30f

typedef __attribute__((ext_vector_type(8))) short     bf16x8;
typedef __attribute__((ext_vector_type(4))) float     f32x4;
typedef __attribute__((ext_vector_type(8))) _Float16  half8;

static __device__ __forceinline__ unsigned short f32_to_bf16(float f) {
    union { float f; uint32_t u; } v; v.f = f;
    const uint32_t u = v.u + 0x7fffu + ((v.u >> 16) & 1u);   // RNE
    return (unsigned short)(u >> 16);
}

// ---------------------------------------------------------------------------
// Kernel 0: prep. For z=0: x, z=1: y. Per (t-chunk of 64, b, z):
//  - stage 128f x 64t f32 tile in LDS (padded stride 65)
//  - nx[b][t] = sum_f x^2 (f32, exact-input precision)
//  - xt[b][t][f] = bf16(x)  (transposed layout, K-contiguous for MFMA frags)
// ---------------------------------------------------------------------------
__global__ __launch_bounds__(256) void dtw_prep_kernel(
    const float* __restrict__ x, const float* __restrict__ y,
    unsigned short* __restrict__ xt, unsigned short* __restrict__ yt,
    float* __restrict__ nx, float* __restrict__ ny)
{
    const int tch = blockIdx.x;
    const int b   = blockIdx.y;
    const int z   = blockIdx.z;
    const int tid = threadIdx.x;
    const int t0  = tch * 64;

    const float* src      = (z == 0 ? x : y) + (size_t)b * F_ * T_;
    unsigned short* dst   = (z == 0 ? xt : yt) + (size_t)b * T_ * F_;
    float* nd             = (z == 0 ? nx : ny) + (size_t)b * T_;

    __shared__ float S[F_][65];

    const int fr = tid >> 4;
    const int q  = (tid & 15) * 4;
#pragma unroll
    for (int p = 0; p < 8; ++p) {
        const int f = p * 16 + fr;
        const float4 v = *(const float4*)(src + (size_t)f * T_ + t0 + q);
        S[f][q] = v.x; S[f][q + 1] = v.y; S[f][q + 2] = v.z; S[f][q + 3] = v.w;
    }
    __syncthreads();

    if (tid < 64) {
        float s = 0.f;
#pragma unroll
        for (int f = 0; f < F_; ++f) { const float v = S[f][tid]; s = fmaf(v, v, s); }
        nd[t0 + tid] = s;
    }

    // pack bf16 rows: thread -> (t = tid>>2, f-block = (tid&3)*32), 64B store
    const int tl = tid >> 2;
    const int fb = (tid & 3) * 32;
    uint32_t pk[16];
#pragma unroll
    for (int e = 0; e < 16; ++e) {
        const uint32_t lo = f32_to_bf16(S[fb + 2 * e][tl]);
        const uint32_t hi = f32_to_bf16(S[fb + 2 * e + 1][tl]);
        pk[e] = lo | (hi << 16);
    }
    uint32_t* o = (uint32_t*)(dst + (size_t)(t0 + tl) * F_ + fb);
#pragma unroll
    for (int e = 0; e < 16; e += 4)
        *(uint4*)(o + e) = make_uint4(pk[e], pk[e + 1], pk[e + 2], pk[e + 3]);
}

// ---------------------------------------------------------------------------
// Kernel 1: cost[b][i][j] = sqrt(max(nx_i + ny_j - 2 * (x_i . y_j), 0))
// cross-term via mfma_f32_16x16x32_bf16 on XOR-swizzled LDS bf16 tiles.
// Written DIAGONAL-MAJOR costD[b][i+j][j] as f16 via the LDS-transpose +
// diagonal-coalesced scatter epilogue.
// grid = (8, 8, Bg), block 256 (4 waves; wave w owns M-strip 16w..16w+15).
// ---------------------------------------------------------------------------
__global__ __launch_bounds__(256) void dtw_cost_kernel(
    const unsigned short* __restrict__ xt, const unsigned short* __restrict__ yt,
    const float* __restrict__ nx, const float* __restrict__ ny,
    unsigned short* __restrict__ costD, int b0)
{
    const int tj  = blockIdx.x;
    const int ti  = blockIdx.y;
    const int bl  = blockIdx.z;
    const int b   = b0 + bl;
    const int tid = threadIdx.x;
    const int gi0 = ti * TS;
    const int gj0 = tj * TS;

    // explicit layout: Xs @0 (16KB), Ys @16K (16KB), x2s @32K, y2s @32K+256.
    // Epilogue overlays Ts (64x68 f32 = 17408 B) on [0, 17408) — Xs+part of Ys,
    // both dead by then; x2s/y2s live beyond offset 32768.
    __shared__ __align__(16) char smem[16384 * 2 + 512];
    unsigned short* Xs = (unsigned short*)smem;
    unsigned short* Ys = (unsigned short*)(smem + 16384);
    float* x2s = (float*)(smem + 32768);
    float* y2s = (float*)(smem + 32768 + 256);

    // stage bf16 tiles (rows: 256B each, 16 lanes x 16B) with XOR swizzle
    {
        const int l16 = tid & 15;
#pragma unroll
        for (int p = 0; p < 4; ++p) {
            const int row = p * 16 + (tid >> 4);
            const uint4 vx = *(const uint4*)(xt + ((size_t)b * T_ + gi0 + row) * F_ + l16 * 8);
            const uint4 vy = *(const uint4*)(yt + ((size_t)b * T_ + gj0 + row) * F_ + l16 * 8);
            const int byt = (row * 256 + l16 * 16) ^ ((row & 7) << 4);
            *(uint4*)((char*)Xs + byt) = vx;
            *(uint4*)((char*)Ys + byt) = vy;
        }
    }
    if (tid < 64)       x2s[tid]      = nx[(size_t)b * T_ + gi0 + tid];
    else if (tid < 128) y2s[tid - 64] = ny[(size_t)b * T_ + gj0 + (tid - 64)];
    __syncthreads();

    const int w    = tid >> 6;
    const int lane = tid & 63;
    const int l15  = lane & 15;
    const int hi   = lane >> 4;

    f32x4 acc[4] = {};
    const int arow = 16 * w + l15;
#pragma unroll
    for (int kb = 0; kb < 4; ++kb) {
        const int koff = kb * 64 + hi * 16;            // byte offset of 8-bf16 frag
        const bf16x8 a = *(const bf16x8*)((const char*)Xs +
                          ((arow * 256 + koff) ^ ((arow & 7) << 4)));
#pragma unroll
        for (int nt = 0; nt < 4; ++nt) {
            const int col = nt * 16 + l15;
            const bf16x8 bb = *(const bf16x8*)((const char*)Ys +
                               ((col * 256 + koff) ^ ((col & 7) << 4)));
            acc[nt] = __builtin_amdgcn_mfma_f32_16x16x32_bf16(a, bb, acc[nt], 0, 0, 0);
        }
    }

    // epilogue: finalize cost, place into Ts[row][col] (stride 68), then
    // diagonal-coalesced scatter (proven round-2 pattern), stored as f16.
    __syncthreads();                        // all MFMA LDS reads complete
    float* Ts = (float*)smem;               // overlay
#pragma unroll
    for (int nt = 0; nt < 4; ++nt) {
        const int col = nt * 16 + l15;
        const float y2v = y2s[col];
#pragma unroll
        for (int r = 0; r < 4; ++r) {
            const int row = 16 * w + hi * 4 + r;
            const float c = sqrtf(fmaxf(x2s[row] + y2v - 2.f * acc[nt][r], 0.f));
            Ts[row * 68 + col] = c;
        }
    }
    __syncthreads();

    unsigned short* outD = costD + (size_t)bl * (DIAG_N * (size_t)T_);
    const int tbase = gi0 + gj0;
#pragma unroll 4
    for (int g = 0; g < 32; ++g) {
        const int tloc = g * 4 + w;        // 0..127
        if (tloc <= 126) {
            const int c0 = tloc > 63 ? tloc - 63 : 0;
            const int c1 = tloc < 63 ? tloc : 63;
            const int c  = c0 + lane;
            if (c <= c1) {
                const _Float16 hv = (_Float16)Ts[68 * (tloc - c) + c];  // RNE cvt
                outD[(size_t)(tbase + tloc) * T_ + gj0 + c] =
                    *(const unsigned short*)&hv;
            }
        }
    }
}

// ---------------------------------------------------------------------------
// Kernel 2: anti-diagonal DTW DP. One 64-lane wave per batch, lane L owns
// columns j = 8L..8L+7 (f16 cost: one dwordx4 load per lane per tick).
// Pipeline is enforced structurally: 16-STEP / 16-LOAD blocks separated by
// sched_barrier(0) so the scheduler cannot sink loads toward uses; each
// STEP's data was issued a full 32-tick block (~2000 cy) earlier and vmcnt
// never drains below 16 outstanding. launch_bounds(64,1) frees the full
// VGPR budget (expect ~160 VGPR; round-4's 88 betrayed a collapsed pipeline).
// ---------------------------------------------------------------------------
__global__ __launch_bounds__(64, 1) void dtw_dp_diag(
    const unsigned short* __restrict__ costD, float* __restrict__ out, int b0)
{
    const int bl = blockIdx.x;
    const int L  = threadIdx.x;
    const unsigned short* base = costD + (size_t)bl * (DIAG_N * (size_t)T_) + 8 * L;

    float v1_0 = BIGV, v1_1 = BIGV, v1_2 = BIGV, v1_3 = BIGV,
          v1_4 = BIGV, v1_5 = BIGV, v1_6 = BIGV, v1_7 = BIGV;
    float v2_0 = BIGV, v2_1 = BIGV, v2_2 = BIGV, v2_3 = BIGV,
          v2_4 = BIGV, v2_5 = BIGV, v2_6 = BIGV;

    float s2c = (L == 0) ? 0.f : BIGV;

    uint4 H[32];   // fully-unrolled constant indices only -> stays in VGPRs

#define LOADH(k, tt) H[k] = *(const uint4*)(base + (size_t)(tt) * T_)

#define STEPH(k) do {                                                       \
    const half8 hh = *(const half8*)&H[k];                                  \
    float s1 = __shfl_up(v1_7, 1);                                          \
    if (L == 0) s1 = BIGV;                                                  \
    const float n0 = (float)hh[0] + fminf(fminf(v1_0, s1),   s2c);          \
    const float n1 = (float)hh[1] + fminf(fminf(v1_1, v1_0), v2_0);         \
    const float n2 = (float)hh[2] + fminf(fminf(v1_2, v1_1), v2_1);         \
    const float n3 = (float)hh[3] + fminf(fminf(v1_3, v1_2), v2_2);         \
    const float n4 = (float)hh[4] + fminf(fminf(v1_4, v1_3), v2_3);         \
    const float n5 = (float)hh[5] + fminf(fminf(v1_5, v1_4), v2_4);         \
    const float n6 = (float)hh[6] + fminf(fminf(v1_6, v1_5), v2_5);         \
    const float n7 = (float)hh[7] + fminf(fminf(v1_7, v1_6), v2_6);         \
    s2c = s1;                                                               \
    v2_0 = v1_0; v2_1 = v1_1; v2_2 = v1_2; v2_3 = v1_3;                     \
    v2_4 = v1_4; v2_5 = v1_5; v2_6 = v1_6;                                  \
    v1_0 = n0; v1_1 = n1; v1_2 = n2; v1_3 = n3;                             \
    v1_4 = n4; v1_5 = n5; v1_6 = n6; v1_7 = n7;                             \
} while (0)

    // prologue: ticks 0..31 in flight
#pragma unroll
    for (int k = 0; k < 32; ++k) LOADH(k, k);

    int t = 0;
#pragma unroll 1
    for (int it = 0; it < 31; ++it) {      // 31*32 = 992 ticks
#pragma unroll
        for (int k = 0; k < 16; ++k) STEPH(k);              // t .. t+15
        __builtin_amdgcn_sched_barrier(0);
#pragma unroll
        for (int k = 0; k < 16; ++k) LOADH(k, t + 32 + k);  // t+32 .. t+47
        __builtin_amdgcn_sched_barrier(0);
#pragma unroll
        for (int k = 16; k < 32; ++k) STEPH(k);             // t+16 .. t+31
        __builtin_amdgcn_sched_barrier(0);
#pragma unroll
        for (int k = 16; k < 32; ++k) LOADH(k, t + 32 + k); // t+48 .. t+63
        __builtin_amdgcn_sched_barrier(0);
        t += 32;
    }
    // t = 992; H[0..15] = ticks 992..1007, H[16..31] = 1008..1023
#pragma unroll
    for (int k = 0; k < 16; ++k) STEPH(k);                  // 992..1007
#pragma unroll
    for (int k = 16; k < 31; ++k) STEPH(k);                 // 1008..1022
    // H[31] (diag 1023, junk row) loaded but never stepped.

    if (L == 63) out[b0 + bl] = v1_7;      // dp[511][511]
#undef LOADH
#undef STEPH
}

// ---------------------------------------------------------------------------
extern "C" void kernel_launch(void* const* d_in, const int* in_sizes, int n_in,
                              void* d_out, int out_size, void* d_ws, size_t ws_size,
                              hipStream_t stream)
{
    const float* x = (const float*)d_in[0];
    const float* y = (const float*)d_in[1];
    float* out = (float*)d_out;

    unsigned short* xt = (unsigned short*)d_ws;
    unsigned short* yt = xt + (size_t)B_ * T_ * F_;
    float* nx = (float*)(yt + (size_t)B_ * T_ * F_);
    float* ny = nx + (size_t)B_ * T_;
    unsigned short* costD = (unsigned short*)(ny + (size_t)B_ * T_);
    const size_t head = (size_t)((char*)costD - (char*)d_ws);

    const size_t perb = (size_t)DIAG_N * T_ * sizeof(unsigned short); // 1 MiB/batch
    int Bg = 8;
    for (int g = 128; g >= 8; g >>= 1)
        if (ws_size >= head + perb * (size_t)g) { Bg = g; break; }

    hipLaunchKernelGGL(dtw_prep_kernel, dim3(T_ / 64, B_, 2), dim3(256), 0, stream,
                       x, y, xt, yt, nx, ny);

    for (int b0 = 0; b0 < B_; b0 += Bg) {
        dim3 gc(T_ / TS, T_ / TS, Bg);
        hipLaunchKernelGGL(dtw_cost_kernel, gc, dim3(256), 0, stream,
                           xt, yt, nx, ny, costD, b0);
        hipLaunchKernelGGL(dtw_dp_diag, dim3(Bg), dim3(64), 0, stream,
                           costD, out, b0);
    }
}

// Round 7
// 155.690 us; speedup vs baseline: 3.8663x; 1.0137x over previous
//
#include <hip/hip_runtime.h>
#include <stdint.h>

#define B_ 128
#define F_ 128
#define T_ 512
#define TS 64
#define DIAG_N 1024   // padded diagonal count (1023 used, row 1023 junk-but-allocated)

// Large finite sentinel instead of INF: survives fast-math, never overflows.
#define BIGV 1e30f

typedef __attribute__((ext_vector_type(8))) short     bf16x8;
typedef __attribute__((ext_vector_type(4))) float     f32x4;
typedef __attribute__((ext_vector_type(8))) _Float16  half8;

static __device__ __forceinline__ unsigned short f32_to_bf16(float f) {
    union { float f; uint32_t u; } v; v.f = f;
    const uint32_t u = v.u + 0x7fffu + ((v.u >> 16) & 1u);   // RNE
    return (unsigned short)(u >> 16);
}

// ---------------------------------------------------------------------------
// Kernel 0: prep. For z=0: x, z=1: y. Per (t-chunk of 64, b, z):
//  - stage 128f x 64t f32 tile in LDS (padded stride 65)
//  - nx[b][t] = sum_f x^2 (f32, exact-input precision)
//  - xt[b][t][f] = bf16(x)  (transposed layout, K-contiguous for MFMA frags)
// (unchanged — passing)
// ---------------------------------------------------------------------------
__global__ __launch_bounds__(256) void dtw_prep_kernel(
    const float* __restrict__ x, const float* __restrict__ y,
    unsigned short* __restrict__ xt, unsigned short* __restrict__ yt,
    float* __restrict__ nx, float* __restrict__ ny)
{
    const int tch = blockIdx.x;
    const int b   = blockIdx.y;
    const int z   = blockIdx.z;
    const int tid = threadIdx.x;
    const int t0  = tch * 64;

    const float* src      = (z == 0 ? x : y) + (size_t)b * F_ * T_;
    unsigned short* dst   = (z == 0 ? xt : yt) + (size_t)b * T_ * F_;
    float* nd             = (z == 0 ? nx : ny) + (size_t)b * T_;

    __shared__ float S[F_][65];

    const int fr = tid >> 4;
    const int q  = (tid & 15) * 4;
#pragma unroll
    for (int p = 0; p < 8; ++p) {
        const int f = p * 16 + fr;
        const float4 v = *(const float4*)(src + (size_t)f * T_ + t0 + q);
        S[f][q] = v.x; S[f][q + 1] = v.y; S[f][q + 2] = v.z; S[f][q + 3] = v.w;
    }
    __syncthreads();

    if (tid < 64) {
        float s = 0.f;
#pragma unroll
        for (int f = 0; f < F_; ++f) { const float v = S[f][tid]; s = fmaf(v, v, s); }
        nd[t0 + tid] = s;
    }

    // pack bf16 rows: thread -> (t = tid>>2, f-block = (tid&3)*32), 64B store
    const int tl = tid >> 2;
    const int fb = (tid & 3) * 32;
    uint32_t pk[16];
#pragma unroll
    for (int e = 0; e < 16; ++e) {
        const uint32_t lo = f32_to_bf16(S[fb + 2 * e][tl]);
        const uint32_t hi = f32_to_bf16(S[fb + 2 * e + 1][tl]);
        pk[e] = lo | (hi << 16);
    }
    uint32_t* o = (uint32_t*)(dst + (size_t)(t0 + tl) * F_ + fb);
#pragma unroll
    for (int e = 0; e < 16; e += 4)
        *(uint4*)(o + e) = make_uint4(pk[e], pk[e + 1], pk[e + 2], pk[e + 3]);
}

// ---------------------------------------------------------------------------
// Kernel 1: cost[b][i][j] = sqrt(max(nx_i + ny_j - 2 * (x_i . y_j), 0))
// cross-term via mfma_f32_16x16x32_bf16 on XOR-swizzled LDS bf16 tiles.
// Written DIAGONAL-MAJOR costD[b][i+j][j] as f16 via the LDS-transpose +
// diagonal-coalesced scatter epilogue. (unchanged — passing)
// ---------------------------------------------------------------------------
__global__ __launch_bounds__(256) void dtw_cost_kernel(
    const unsigned short* __restrict__ xt, const unsigned short* __restrict__ yt,
    const float* __restrict__ nx, const float* __restrict__ ny,
    unsigned short* __restrict__ costD, int b0)
{
    const int tj  = blockIdx.x;
    const int ti  = blockIdx.y;
    const int bl  = blockIdx.z;
    const int b   = b0 + bl;
    const int tid = threadIdx.x;
    const int gi0 = ti * TS;
    const int gj0 = tj * TS;

    __shared__ __align__(16) char smem[16384 * 2 + 512];
    unsigned short* Xs = (unsigned short*)smem;
    unsigned short* Ys = (unsigned short*)(smem + 16384);
    float* x2s = (float*)(smem + 32768);
    float* y2s = (float*)(smem + 32768 + 256);

    {
        const int l16 = tid & 15;
#pragma unroll
        for (int p = 0; p < 4; ++p) {
            const int row = p * 16 + (tid >> 4);
            const uint4 vx = *(const uint4*)(xt + ((size_t)b * T_ + gi0 + row) * F_ + l16 * 8);
            const uint4 vy = *(const uint4*)(yt + ((size_t)b * T_ + gj0 + row) * F_ + l16 * 8);
            const int byt = (row * 256 + l16 * 16) ^ ((row & 7) << 4);
            *(uint4*)((char*)Xs + byt) = vx;
            *(uint4*)((char*)Ys + byt) = vy;
        }
    }
    if (tid < 64)       x2s[tid]      = nx[(size_t)b * T_ + gi0 + tid];
    else if (tid < 128) y2s[tid - 64] = ny[(size_t)b * T_ + gj0 + (tid - 64)];
    __syncthreads();

    const int w    = tid >> 6;
    const int lane = tid & 63;
    const int l15  = lane & 15;
    const int hi   = lane >> 4;

    f32x4 acc[4] = {};
    const int arow = 16 * w + l15;
#pragma unroll
    for (int kb = 0; kb < 4; ++kb) {
        const int koff = kb * 64 + hi * 16;
        const bf16x8 a = *(const bf16x8*)((const char*)Xs +
                          ((arow * 256 + koff) ^ ((arow & 7) << 4)));
#pragma unroll
        for (int nt = 0; nt < 4; ++nt) {
            const int col = nt * 16 + l15;
            const bf16x8 bb = *(const bf16x8*)((const char*)Ys +
                               ((col * 256 + koff) ^ ((col & 7) << 4)));
            acc[nt] = __builtin_amdgcn_mfma_f32_16x16x32_bf16(a, bb, acc[nt], 0, 0, 0);
        }
    }

    __syncthreads();                        // all MFMA LDS reads complete
    float* Ts = (float*)smem;               // overlay
#pragma unroll
    for (int nt = 0; nt < 4; ++nt) {
        const int col = nt * 16 + l15;
        const float y2v = y2s[col];
#pragma unroll
        for (int r = 0; r < 4; ++r) {
            const int row = 16 * w + hi * 4 + r;
            const float c = sqrtf(fmaxf(x2s[row] + y2v - 2.f * acc[nt][r], 0.f));
            Ts[row * 68 + col] = c;
        }
    }
    __syncthreads();

    unsigned short* outD = costD + (size_t)bl * (DIAG_N * (size_t)T_);
    const int tbase = gi0 + gj0;
#pragma unroll 4
    for (int g = 0; g < 32; ++g) {
        const int tloc = g * 4 + w;        // 0..127
        if (tloc <= 126) {
            const int c0 = tloc > 63 ? tloc - 63 : 0;
            const int c1 = tloc < 63 ? tloc : 63;
            const int c  = c0 + lane;
            if (c <= c1) {
                const _Float16 hv = (_Float16)Ts[68 * (tloc - c) + c];  // RNE cvt
                outD[(size_t)(tbase + tloc) * T_ + gj0 + c] =
                    *(const unsigned short*)&hv;
            }
        }
    }
}

// ---------------------------------------------------------------------------
// Kernel 2: anti-diagonal DTW DP with a 32-row LDS ring staged by
// global_load_lds (direct-to-LDS DMA). One 64-lane wave per batch; lane L
// owns columns j = 8L..8L+7. One diag row = 512 f16 = 1024 B = 64 lanes x
// 16 B = exactly one global_load_lds(width=16): per-lane global address
// row + 16L bytes, HW lane-scatter lands it at slot + 16L — the row layout.
// Per 8-tick block: counted s_waitcnt vmcnt(24) (never 0 in the main loop),
// 8x {ds_read_b128 + STEP}, then 8 refill loads. No raw asm loads (round 6's
// crash), no compiler-collapsible register pipeline (rounds 4/5).
// ---------------------------------------------------------------------------
__global__ __launch_bounds__(64, 1) void dtw_dp_diag(
    const unsigned short* __restrict__ costD, float* __restrict__ out, int b0)
{
    const int bl = blockIdx.x;
    const int L  = threadIdx.x;
    // per-lane global address of this lane's 16B within each diag row
    const unsigned short* gbase = costD + (size_t)bl * (DIAG_N * (size_t)T_) + 8 * L;

    __shared__ __align__(16) unsigned short ring[32][T_];   // 32 KB

    // ping-pong DP banks: va = diag t-1, vb = diag t-2 (roles swap each tick)
    float va0 = BIGV, va1 = BIGV, va2 = BIGV, va3 = BIGV,
          va4 = BIGV, va5 = BIGV, va6 = BIGV, va7 = BIGV;
    float vb0 = BIGV, vb1 = BIGV, vb2 = BIGV, vb3 = BIGV,
          vb4 = BIGV, vb5 = BIGV, vb6 = BIGV, vb7 = BIGV;

    // s2 for tick t equals s1 from tick t-1; lane-0 seed 0 = dp[-1][-1] start
    float s2c = (L == 0) ? 0.f : BIGV;

#define GLD(row, slot)                                                      \
    __builtin_amdgcn_global_load_lds(                                       \
        (const __attribute__((address_space(1))) void*)(gbase + (size_t)(row) * T_), \
        (__attribute__((address_space(3))) void*)(&ring[slot][0]), 16, 0, 0)

#define WAITV(n)                                                            \
    do { asm volatile("s_waitcnt vmcnt(" #n ")" ::: "memory");              \
         __builtin_amdgcn_sched_barrier(0); } while (0)

    // STEP_A: v1 = va, v2 = vb; result becomes new v1 stored in vb bank.
#define STEP_A(P) do {                                                      \
    const half8 hh = *(const half8*)(P);                                    \
    float s1 = __shfl_up(va7, 1);                                           \
    if (L == 0) s1 = BIGV;                                                  \
    const float n0 = (float)hh[0] + fminf(fminf(va0, s1),  s2c);            \
    const float n1 = (float)hh[1] + fminf(fminf(va1, va0), vb0);            \
    const float n2 = (float)hh[2] + fminf(fminf(va2, va1), vb1);            \
    const float n3 = (float)hh[3] + fminf(fminf(va3, va2), vb2);            \
    const float n4 = (float)hh[4] + fminf(fminf(va4, va3), vb3);            \
    const float n5 = (float)hh[5] + fminf(fminf(va5, va4), vb4);            \
    const float n6 = (float)hh[6] + fminf(fminf(va6, va5), vb5);            \
    const float n7 = (float)hh[7] + fminf(fminf(va7, va6), vb6);            \
    s2c = s1;                                                               \
    vb0 = n0; vb1 = n1; vb2 = n2; vb3 = n3;                                 \
    vb4 = n4; vb5 = n5; vb6 = n6; vb7 = n7;                                 \
} while (0)

    // STEP_B: v1 = vb, v2 = va; result stored in va bank.
#define STEP_B(P) do {                                                      \
    const half8 hh = *(const half8*)(P);                                    \
    float s1 = __shfl_up(vb7, 1);                                           \
    if (L == 0) s1 = BIGV;                                                  \
    const float n0 = (float)hh[0] + fminf(fminf(vb0, s1),  s2c);            \
    const float n1 = (float)hh[1] + fminf(fminf(vb1, vb0), va0);            \
    const float n2 = (float)hh[2] + fminf(fminf(vb2, vb1), va1);            \
    const float n3 = (float)hh[3] + fminf(fminf(vb3, vb2), va2);            \
    const float n4 = (float)hh[4] + fminf(fminf(vb4, vb3), va3);            \
    const float n5 = (float)hh[5] + fminf(fminf(vb5, vb4), va4);            \
    const float n6 = (float)hh[6] + fminf(fminf(vb6, vb5), va5);            \
    const float n7 = (float)hh[7] + fminf(fminf(vb7, vb6), va6);            \
    s2c = s1;                                                               \
    va0 = n0; va1 = n1; va2 = n2; va3 = n3;                                 \
    va4 = n4; va5 = n5; va6 = n6; va7 = n7;                                 \
} while (0)

#define STEP8(rs)                                                           \
    STEP_A((rs) + 0 * T_); STEP_B((rs) + 1 * T_);                           \
    STEP_A((rs) + 2 * T_); STEP_B((rs) + 3 * T_);                           \
    STEP_A((rs) + 4 * T_); STEP_B((rs) + 5 * T_);                           \
    STEP_A((rs) + 6 * T_); STEP_B((rs) + 7 * T_)

    // prologue: rows 0..31 in flight into slots 0..31
#pragma unroll
    for (int r = 0; r < 32; ++r) GLD(r, r);

    int t = 0;
#pragma unroll 1
    for (int k = 0; k < 124; ++k) {        // ticks 0..991, loads rows 32..1023
        WAITV(24);                         // rows t..t+7 landed in LDS
        const unsigned short* rs = &ring[t & 31][8 * L];
        STEP8(rs);
        __builtin_amdgcn_sched_barrier(0);
        const int s0 = t & 31;             // slots just consumed -> refill
        GLD(t + 32, s0);     GLD(t + 33, s0 + 1);
        GLD(t + 34, s0 + 2); GLD(t + 35, s0 + 3);
        GLD(t + 36, s0 + 4); GLD(t + 37, s0 + 5);
        GLD(t + 38, s0 + 6); GLD(t + 39, s0 + 7);
        __builtin_amdgcn_sched_barrier(0);
        t += 8;
    }
    // t = 992; remaining rows 992..1023 are in flight/landed (slots 0..31)
    WAITV(24); { const unsigned short* rs = &ring[0][8 * L];  STEP8(rs); }  // 992..999
    WAITV(16); { const unsigned short* rs = &ring[8][8 * L];  STEP8(rs); }  // 1000..1007
    WAITV(8);  { const unsigned short* rs = &ring[16][8 * L]; STEP8(rs); }  // 1008..1015
    WAITV(0);                                                               // 1016..1022
    {
        const unsigned short* rs = &ring[24][8 * L];
        STEP_A(rs + 0 * T_); STEP_B(rs + 1 * T_);
        STEP_A(rs + 2 * T_); STEP_B(rs + 3 * T_);
        STEP_A(rs + 4 * T_); STEP_B(rs + 5 * T_);
        STEP_A(rs + 6 * T_);               // tick 1022, result in vb bank
        // slot 31 (diag 1023, junk row) staged but never stepped.
    }

    if (L == 63) out[b0 + bl] = vb7;       // dp[511][511]
#undef GLD
#undef WAITV
#undef STEP_A
#undef STEP_B
#undef STEP8
}

// ---------------------------------------------------------------------------
extern "C" void kernel_launch(void* const* d_in, const int* in_sizes, int n_in,
                              void* d_out, int out_size, void* d_ws, size_t ws_size,
                              hipStream_t stream)
{
    const float* x = (const float*)d_in[0];
    const float* y = (const float*)d_in[1];
    float* out = (float*)d_out;

    unsigned short* xt = (unsigned short*)d_ws;
    unsigned short* yt = xt + (size_t)B_ * T_ * F_;
    float* nx = (float*)(yt + (size_t)B_ * T_ * F_);
    float* ny = nx + (size_t)B_ * T_;
    unsigned short* costD = (unsigned short*)(ny + (size_t)B_ * T_);
    const size_t head = (size_t)((char*)costD - (char*)d_ws);

    const size_t perb = (size_t)DIAG_N * T_ * sizeof(unsigned short); // 1 MiB/batch
    int Bg = 8;
    for (int g = 128; g >= 8; g >>= 1)
        if (ws_size >= head + perb * (size_t)g) { Bg = g; break; }

    hipLaunchKernelGGL(dtw_prep_kernel, dim3(T_ / 64, B_, 2), dim3(256), 0, stream,
                       x, y, xt, yt, nx, ny);

    for (int b0 = 0; b0 < B_; b0 += Bg) {
        dim3 gc(T_ / TS, T_ / TS, Bg);
        hipLaunchKernelGGL(dtw_cost_kernel, gc, dim3(256), 0, stream,
                           xt, yt, nx, ny, costD, b0);
        hipLaunchKernelGGL(dtw_dp_diag, dim3(Bg), dim3(64), 0, stream,
                           costD, out, b0);
    }
}

// Round 8
// 148.343 us; speedup vs baseline: 4.0578x; 1.0495x over previous
//
#include <hip/hip_runtime.h>
#include <stdint.h>

#define B_ 128
#define F_ 128
#define T_ 512
#define TS 64
#define DIAG_N 1024   // padded diagonal count (1023 used, row 1023 junk-but-allocated)

// Large finite sentinel instead of INF: survives fast-math, never overflows.
#define BIGV 1e30f

typedef __attribute__((ext_vector_type(8))) short     bf16x8;
typedef __attribute__((ext_vector_type(4))) float     f32x4;
typedef __attribute__((ext_vector_type(8))) _Float16  half8;

static __device__ __forceinline__ unsigned short f32_to_bf16(float f) {
    union { float f; uint32_t u; } v; v.f = f;
    const uint32_t u = v.u + 0x7fffu + ((v.u >> 16) & 1u);   // RNE
    return (unsigned short)(u >> 16);
}

// DPP wave_shr:1 — whole-wave shift up by one lane in a single VALU op.
// bound_ctrl=false => lane 0 (no source) keeps `fill`. Replaces
// ds_bpermute-based __shfl_up (+ its lgkmcnt wait) on the serial recurrence.
static __device__ __forceinline__ float wave_shr1(float src, float fill) {
    const int r = __builtin_amdgcn_update_dpp(
        __builtin_bit_cast(int, fill), __builtin_bit_cast(int, src),
        0x138 /* wave_shr:1 */, 0xf, 0xf, false);
    return __builtin_bit_cast(float, r);
}

// ---------------------------------------------------------------------------
// Kernel 0: prep. For z=0: x, z=1: y. Per (t-chunk of 64, b, z):
//  - stage 128f x 64t f32 tile in LDS (padded stride 65)
//  - nx[b][t] = sum_f x^2 (f32, exact-input precision)
//  - xt[b][t][f] = bf16(x)  (transposed layout, K-contiguous for MFMA frags)
// (unchanged — passing)
// ---------------------------------------------------------------------------
__global__ __launch_bounds__(256) void dtw_prep_kernel(
    const float* __restrict__ x, const float* __restrict__ y,
    unsigned short* __restrict__ xt, unsigned short* __restrict__ yt,
    float* __restrict__ nx, float* __restrict__ ny)
{
    const int tch = blockIdx.x;
    const int b   = blockIdx.y;
    const int z   = blockIdx.z;
    const int tid = threadIdx.x;
    const int t0  = tch * 64;

    const float* src      = (z == 0 ? x : y) + (size_t)b * F_ * T_;
    unsigned short* dst   = (z == 0 ? xt : yt) + (size_t)b * T_ * F_;
    float* nd             = (z == 0 ? nx : ny) + (size_t)b * T_;

    __shared__ float S[F_][65];

    const int fr = tid >> 4;
    const int q  = (tid & 15) * 4;
#pragma unroll
    for (int p = 0; p < 8; ++p) {
        const int f = p * 16 + fr;
        const float4 v = *(const float4*)(src + (size_t)f * T_ + t0 + q);
        S[f][q] = v.x; S[f][q + 1] = v.y; S[f][q + 2] = v.z; S[f][q + 3] = v.w;
    }
    __syncthreads();

    if (tid < 64) {
        float s = 0.f;
#pragma unroll
        for (int f = 0; f < F_; ++f) { const float v = S[f][tid]; s = fmaf(v, v, s); }
        nd[t0 + tid] = s;
    }

    // pack bf16 rows: thread -> (t = tid>>2, f-block = (tid&3)*32), 64B store
    const int tl = tid >> 2;
    const int fb = (tid & 3) * 32;
    uint32_t pk[16];
#pragma unroll
    for (int e = 0; e < 16; ++e) {
        const uint32_t lo = f32_to_bf16(S[fb + 2 * e][tl]);
        const uint32_t hi = f32_to_bf16(S[fb + 2 * e + 1][tl]);
        pk[e] = lo | (hi << 16);
    }
    uint32_t* o = (uint32_t*)(dst + (size_t)(t0 + tl) * F_ + fb);
#pragma unroll
    for (int e = 0; e < 16; e += 4)
        *(uint4*)(o + e) = make_uint4(pk[e], pk[e + 1], pk[e + 2], pk[e + 3]);
}

// ---------------------------------------------------------------------------
// Kernel 1: cost[b][i][j] = sqrt(max(nx_i + ny_j - 2 * (x_i . y_j), 0))
// cross-term via mfma_f32_16x16x32_bf16 on XOR-swizzled LDS bf16 tiles.
// Written DIAGONAL-MAJOR costD[b][i+j][j] as f16 via the LDS-transpose +
// diagonal-coalesced scatter epilogue. (unchanged — passing)
// ---------------------------------------------------------------------------
__global__ __launch_bounds__(256) void dtw_cost_kernel(
    const unsigned short* __restrict__ xt, const unsigned short* __restrict__ yt,
    const float* __restrict__ nx, const float* __restrict__ ny,
    unsigned short* __restrict__ costD, int b0)
{
    const int tj  = blockIdx.x;
    const int ti  = blockIdx.y;
    const int bl  = blockIdx.z;
    const int b   = b0 + bl;
    const int tid = threadIdx.x;
    const int gi0 = ti * TS;
    const int gj0 = tj * TS;

    __shared__ __align__(16) char smem[16384 * 2 + 512];
    unsigned short* Xs = (unsigned short*)smem;
    unsigned short* Ys = (unsigned short*)(smem + 16384);
    float* x2s = (float*)(smem + 32768);
    float* y2s = (float*)(smem + 32768 + 256);

    {
        const int l16 = tid & 15;
#pragma unroll
        for (int p = 0; p < 4; ++p) {
            const int row = p * 16 + (tid >> 4);
            const uint4 vx = *(const uint4*)(xt + ((size_t)b * T_ + gi0 + row) * F_ + l16 * 8);
            const uint4 vy = *(const uint4*)(yt + ((size_t)b * T_ + gj0 + row) * F_ + l16 * 8);
            const int byt = (row * 256 + l16 * 16) ^ ((row & 7) << 4);
            *(uint4*)((char*)Xs + byt) = vx;
            *(uint4*)((char*)Ys + byt) = vy;
        }
    }
    if (tid < 64)       x2s[tid]      = nx[(size_t)b * T_ + gi0 + tid];
    else if (tid < 128) y2s[tid - 64] = ny[(size_t)b * T_ + gj0 + (tid - 64)];
    __syncthreads();

    const int w    = tid >> 6;
    const int lane = tid & 63;
    const int l15  = lane & 15;
    const int hi   = lane >> 4;

    f32x4 acc[4] = {};
    const int arow = 16 * w + l15;
#pragma unroll
    for (int kb = 0; kb < 4; ++kb) {
        const int koff = kb * 64 + hi * 16;
        const bf16x8 a = *(const bf16x8*)((const char*)Xs +
                          ((arow * 256 + koff) ^ ((arow & 7) << 4)));
#pragma unroll
        for (int nt = 0; nt < 4; ++nt) {
            const int col = nt * 16 + l15;
            const bf16x8 bb = *(const bf16x8*)((const char*)Ys +
                               ((col * 256 + koff) ^ ((col & 7) << 4)));
            acc[nt] = __builtin_amdgcn_mfma_f32_16x16x32_bf16(a, bb, acc[nt], 0, 0, 0);
        }
    }

    __syncthreads();                        // all MFMA LDS reads complete
    float* Ts = (float*)smem;               // overlay
#pragma unroll
    for (int nt = 0; nt < 4; ++nt) {
        const int col = nt * 16 + l15;
        const float y2v = y2s[col];
#pragma unroll
        for (int r = 0; r < 4; ++r) {
            const int row = 16 * w + hi * 4 + r;
            const float c = sqrtf(fmaxf(x2s[row] + y2v - 2.f * acc[nt][r], 0.f));
            Ts[row * 68 + col] = c;
        }
    }
    __syncthreads();

    unsigned short* outD = costD + (size_t)bl * (DIAG_N * (size_t)T_);
    const int tbase = gi0 + gj0;
#pragma unroll 4
    for (int g = 0; g < 32; ++g) {
        const int tloc = g * 4 + w;        // 0..127
        if (tloc <= 126) {
            const int c0 = tloc > 63 ? tloc - 63 : 0;
            const int c1 = tloc < 63 ? tloc : 63;
            const int c  = c0 + lane;
            if (c <= c1) {
                const _Float16 hv = (_Float16)Ts[68 * (tloc - c) + c];  // RNE cvt
                outD[(size_t)(tbase + tloc) * T_ + gj0 + c] =
                    *(const unsigned short*)&hv;
            }
        }
    }
}

// ---------------------------------------------------------------------------
// Kernel 2: anti-diagonal DTW DP with a 32-row LDS ring staged by
// global_load_lds. One 64-lane wave per batch; lane L owns columns
// j = 8L..8L+7. Per 8-tick block: counted s_waitcnt vmcnt(24) (never 0 in
// the main loop), 8x {ds_read_b128 + STEP}, then 8 refill loads.
// Round 8 change: the serial cross-tick lane-shift uses DPP wave_shr:1
// (single VALU op, lane0 filled with BIGV via bound_ctrl old-value) instead
// of ds_bpermute — removes ~40cy DS latency + in-order lgkmcnt entanglement
// with the ring ds_reads from the per-tick critical path.
// ---------------------------------------------------------------------------
__global__ __launch_bounds__(64, 1) void dtw_dp_diag(
    const unsigned short* __restrict__ costD, float* __restrict__ out, int b0)
{
    const int bl = blockIdx.x;
    const int L  = threadIdx.x;
    // per-lane global address of this lane's 16B within each diag row
    const unsigned short* gbase = costD + (size_t)bl * (DIAG_N * (size_t)T_) + 8 * L;

    __shared__ __align__(16) unsigned short ring[32][T_];   // 32 KB

    // ping-pong DP banks: va = diag t-1, vb = diag t-2 (roles swap each tick)
    float va0 = BIGV, va1 = BIGV, va2 = BIGV, va3 = BIGV,
          va4 = BIGV, va5 = BIGV, va6 = BIGV, va7 = BIGV;
    float vb0 = BIGV, vb1 = BIGV, vb2 = BIGV, vb3 = BIGV,
          vb4 = BIGV, vb5 = BIGV, vb6 = BIGV, vb7 = BIGV;

    // s2 for tick t equals s1 from tick t-1; lane-0 seed 0 = dp[-1][-1] start
    float s2c = (L == 0) ? 0.f : BIGV;

#define GLD(row, slot)                                                      \
    __builtin_amdgcn_global_load_lds(                                       \
        (const __attribute__((address_space(1))) void*)(gbase + (size_t)(row) * T_), \
        (__attribute__((address_space(3))) void*)(&ring[slot][0]), 16, 0, 0)

#define WAITV(n)                                                            \
    do { asm volatile("s_waitcnt vmcnt(" #n ")" ::: "memory");              \
         __builtin_amdgcn_sched_barrier(0); } while (0)

    // STEP_A: v1 = va, v2 = vb; result becomes new v1 stored in vb bank.
#define STEP_A(P) do {                                                      \
    const half8 hh = *(const half8*)(P);                                    \
    const float s1 = wave_shr1(va7, BIGV);                                  \
    const float n0 = (float)hh[0] + fminf(fminf(va0, s1),  s2c);            \
    const float n1 = (float)hh[1] + fminf(fminf(va1, va0), vb0);            \
    const float n2 = (float)hh[2] + fminf(fminf(va2, va1), vb1);            \
    const float n3 = (float)hh[3] + fminf(fminf(va3, va2), vb2);            \
    const float n4 = (float)hh[4] + fminf(fminf(va4, va3), vb3);            \
    const float n5 = (float)hh[5] + fminf(fminf(va5, va4), vb4);            \
    const float n6 = (float)hh[6] + fminf(fminf(va6, va5), vb5);            \
    const float n7 = (float)hh[7] + fminf(fminf(va7, va6), vb6);            \
    s2c = s1;                                                               \
    vb0 = n0; vb1 = n1; vb2 = n2; vb3 = n3;                                 \
    vb4 = n4; vb5 = n5; vb6 = n6; vb7 = n7;                                 \
} while (0)

    // STEP_B: v1 = vb, v2 = va; result stored in va bank.
#define STEP_B(P) do {                                                      \
    const half8 hh = *(const half8*)(P);                                    \
    const float s1 = wave_shr1(vb7, BIGV);                                  \
    const float n0 = (float)hh[0] + fminf(fminf(vb0, s1),  s2c);            \
    const float n1 = (float)hh[1] + fminf(fminf(vb1, vb0), va0);            \
    const float n2 = (float)hh[2] + fminf(fminf(vb2, vb1), va1);            \
    const float n3 = (float)hh[3] + fminf(fminf(vb3, vb2), va2);            \
    const float n4 = (float)hh[4] + fminf(fminf(vb4, vb3), va3);            \
    const float n5 = (float)hh[5] + fminf(fminf(vb5, vb4), va4);            \
    const float n6 = (float)hh[6] + fminf(fminf(vb6, vb5), va5);            \
    const float n7 = (float)hh[7] + fminf(fminf(vb7, vb6), va6);            \
    s2c = s1;                                                               \
    va0 = n0; va1 = n1; va2 = n2; va3 = n3;                                 \
    va4 = n4; va5 = n5; va6 = n6; va7 = n7;                                 \
} while (0)

#define STEP8(rs)                                                           \
    STEP_A((rs) + 0 * T_); STEP_B((rs) + 1 * T_);                           \
    STEP_A((rs) + 2 * T_); STEP_B((rs) + 3 * T_);                           \
    STEP_A((rs) + 4 * T_); STEP_B((rs) + 5 * T_);                           \
    STEP_A((rs) + 6 * T_); STEP_B((rs) + 7 * T_)

    // prologue: rows 0..31 in flight into slots 0..31
#pragma unroll
    for (int r = 0; r < 32; ++r) GLD(r, r);

    int t = 0;
#pragma unroll 1
    for (int k = 0; k < 124; ++k) {        // ticks 0..991, loads rows 32..1023
        WAITV(24);                         // rows t..t+7 landed in LDS
        const unsigned short* rs = &ring[t & 31][8 * L];
        STEP8(rs);
        __builtin_amdgcn_sched_barrier(0);
        const int s0 = t & 31;             // slots just consumed -> refill
        GLD(t + 32, s0);     GLD(t + 33, s0 + 1);
        GLD(t + 34, s0 + 2); GLD(t + 35, s0 + 3);
        GLD(t + 36, s0 + 4); GLD(t + 37, s0 + 5);
        GLD(t + 38, s0 + 6); GLD(t + 39, s0 + 7);
        __builtin_amdgcn_sched_barrier(0);
        t += 8;
    }
    // t = 992; remaining rows 992..1023 are in flight/landed (slots 0..31)
    WAITV(24); { const unsigned short* rs = &ring[0][8 * L];  STEP8(rs); }  // 992..999
    WAITV(16); { const unsigned short* rs = &ring[8][8 * L];  STEP8(rs); }  // 1000..1007
    WAITV(8);  { const unsigned short* rs = &ring[16][8 * L]; STEP8(rs); }  // 1008..1015
    WAITV(0);                                                               // 1016..1022
    {
        const unsigned short* rs = &ring[24][8 * L];
        STEP_A(rs + 0 * T_); STEP_B(rs + 1 * T_);
        STEP_A(rs + 2 * T_); STEP_B(rs + 3 * T_);
        STEP_A(rs + 4 * T_); STEP_B(rs + 5 * T_);
        STEP_A(rs + 6 * T_);               // tick 1022, result in vb bank
        // slot 31 (diag 1023, junk row) staged but never stepped.
    }

    if (L == 63) out[b0 + bl] = vb7;       // dp[511][511]
#undef GLD
#undef WAITV
#undef STEP_A
#undef STEP_B
#undef STEP8
}

// ---------------------------------------------------------------------------
extern "C" void kernel_launch(void* const* d_in, const int* in_sizes, int n_in,
                              void* d_out, int out_size, void* d_ws, size_t ws_size,
                              hipStream_t stream)
{
    const float* x = (const float*)d_in[0];
    const float* y = (const float*)d_in[1];
    float* out = (float*)d_out;

    unsigned short* xt = (unsigned short*)d_ws;
    unsigned short* yt = xt + (size_t)B_ * T_ * F_;
    float* nx = (float*)(yt + (size_t)B_ * T_ * F_);
    float* ny = nx + (size_t)B_ * T_;
    unsigned short* costD = (unsigned short*)(ny + (size_t)B_ * T_);
    const size_t head = (size_t)((char*)costD - (char*)d_ws);

    const size_t perb = (size_t)DIAG_N * T_ * sizeof(unsigned short); // 1 MiB/batch
    int Bg = 8;
    for (int g = 128; g >= 8; g >>= 1)
        if (ws_size >= head + perb * (size_t)g) { Bg = g; break; }

    hipLaunchKernelGGL(dtw_prep_kernel, dim3(T_ / 64, B_, 2), dim3(256), 0, stream,
                       x, y, xt, yt, nx, ny);

    for (int b0 = 0; b0 < B_; b0 += Bg) {
        dim3 gc(T_ / TS, T_ / TS, Bg);
        hipLaunchKernelGGL(dtw_cost_kernel, gc, dim3(256), 0, stream,
                           xt, yt, nx, ny, costD, b0);
        hipLaunchKernelGGL(dtw_dp_diag, dim3(Bg), dim3(64), 0, stream,
                           costD, out, b0);
    }
}

// Round 9
// 139.805 us; speedup vs baseline: 4.3056x; 1.0611x over previous
//
#include <hip/hip_runtime.h>
#include <stdint.h>

#define B_ 128
#define F_ 128
#define T_ 512
#define TS 64
#define DIAG_N 1024   // padded diagonal count (1023 used, row 1023 junk-but-allocated)

// Large finite sentinel instead of INF: survives fast-math, never overflows.
#define BIGV 1e30f

typedef __attribute__((ext_vector_type(8))) short     bf16x8;
typedef __attribute__((ext_vector_type(4))) float     f32x4;
typedef __attribute__((ext_vector_type(8))) _Float16  half8;

static __device__ __forceinline__ unsigned short f32_to_bf16(float f) {
    union { float f; uint32_t u; } v; v.f = f;
    const uint32_t u = v.u + 0x7fffu + ((v.u >> 16) & 1u);   // RNE
    return (unsigned short)(u >> 16);
}

// DPP wave_shr:1 — whole-wave shift up by one lane in a single VALU op.
// bound_ctrl=false => lane 0 (no source) keeps `fill`.
static __device__ __forceinline__ float wave_shr1(float src, float fill) {
    const int r = __builtin_amdgcn_update_dpp(
        __builtin_bit_cast(int, fill), __builtin_bit_cast(int, src),
        0x138 /* wave_shr:1 */, 0xf, 0xf, false);
    return __builtin_bit_cast(float, r);
}

// ---------------------------------------------------------------------------
// Kernel 0: prep (unchanged — passing). Transpose to bf16 [b][t][f] + f32
// squared norms.
// ---------------------------------------------------------------------------
__global__ __launch_bounds__(256) void dtw_prep_kernel(
    const float* __restrict__ x, const float* __restrict__ y,
    unsigned short* __restrict__ xt, unsigned short* __restrict__ yt,
    float* __restrict__ nx, float* __restrict__ ny)
{
    const int tch = blockIdx.x;
    const int b   = blockIdx.y;
    const int z   = blockIdx.z;
    const int tid = threadIdx.x;
    const int t0  = tch * 64;

    const float* src      = (z == 0 ? x : y) + (size_t)b * F_ * T_;
    unsigned short* dst   = (z == 0 ? xt : yt) + (size_t)b * T_ * F_;
    float* nd             = (z == 0 ? nx : ny) + (size_t)b * T_;

    __shared__ float S[F_][65];

    const int fr = tid >> 4;
    const int q  = (tid & 15) * 4;
#pragma unroll
    for (int p = 0; p < 8; ++p) {
        const int f = p * 16 + fr;
        const float4 v = *(const float4*)(src + (size_t)f * T_ + t0 + q);
        S[f][q] = v.x; S[f][q + 1] = v.y; S[f][q + 2] = v.z; S[f][q + 3] = v.w;
    }
    __syncthreads();

    if (tid < 64) {
        float s = 0.f;
#pragma unroll
        for (int f = 0; f < F_; ++f) { const float v = S[f][tid]; s = fmaf(v, v, s); }
        nd[t0 + tid] = s;
    }

    const int tl = tid >> 2;
    const int fb = (tid & 3) * 32;
    uint32_t pk[16];
#pragma unroll
    for (int e = 0; e < 16; ++e) {
        const uint32_t lo = f32_to_bf16(S[fb + 2 * e][tl]);
        const uint32_t hi = f32_to_bf16(S[fb + 2 * e + 1][tl]);
        pk[e] = lo | (hi << 16);
    }
    uint32_t* o = (uint32_t*)(dst + (size_t)(t0 + tl) * F_ + fb);
#pragma unroll
    for (int e = 0; e < 16; e += 4)
        *(uint4*)(o + e) = make_uint4(pk[e], pk[e + 1], pk[e + 2], pk[e + 3]);
}

// ---------------------------------------------------------------------------
// Kernel 1: cost via mfma_f32_16x16x32_bf16, diagonal-major f16 output.
// Round 9 trims: norms straight global->regs (no x2s/y2s LDS; smem = 32 KB
// exactly -> 5 blocks/CU), Ts transpose buffer in f16 (stride 68 halfwords,
// ~2 lanes/bank both ways; cvt done once before transpose), scatter uses
// clamped c = min(c0+lane, c1) with benign duplicate stores instead of
// exec-mask predication.
// ---------------------------------------------------------------------------
__global__ __launch_bounds__(256) void dtw_cost_kernel(
    const unsigned short* __restrict__ xt, const unsigned short* __restrict__ yt,
    const float* __restrict__ nx, const float* __restrict__ ny,
    unsigned short* __restrict__ costD, int b0)
{
    const int tj  = blockIdx.x;
    const int ti  = blockIdx.y;
    const int bl  = blockIdx.z;
    const int b   = b0 + bl;
    const int tid = threadIdx.x;
    const int gi0 = ti * TS;
    const int gj0 = tj * TS;

    // Xs @0 (16KB), Ys @16K (16KB). Ts (f16, 64 x stride-68 = 8704 B)
    // overlays Xs after the MFMA phase.
    __shared__ __align__(16) char smem[32768];
    unsigned short* Xs = (unsigned short*)smem;
    unsigned short* Ys = (unsigned short*)(smem + 16384);

    {
        const int l16 = tid & 15;
#pragma unroll
        for (int p = 0; p < 4; ++p) {
            const int row = p * 16 + (tid >> 4);
            const uint4 vx = *(const uint4*)(xt + ((size_t)b * T_ + gi0 + row) * F_ + l16 * 8);
            const uint4 vy = *(const uint4*)(yt + ((size_t)b * T_ + gj0 + row) * F_ + l16 * 8);
            const int byt = (row * 256 + l16 * 16) ^ ((row & 7) << 4);
            *(uint4*)((char*)Xs + byt) = vx;
            *(uint4*)((char*)Ys + byt) = vy;
        }
    }
    __syncthreads();

    const int w    = tid >> 6;
    const int lane = tid & 63;
    const int l15  = lane & 15;
    const int hi   = lane >> 4;

    f32x4 acc[4] = {};
    const int arow = 16 * w + l15;
#pragma unroll
    for (int kb = 0; kb < 4; ++kb) {
        const int koff = kb * 64 + hi * 16;
        const bf16x8 a = *(const bf16x8*)((const char*)Xs +
                          ((arow * 256 + koff) ^ ((arow & 7) << 4)));
#pragma unroll
        for (int nt = 0; nt < 4; ++nt) {
            const int col = nt * 16 + l15;
            const bf16x8 bb = *(const bf16x8*)((const char*)Ys +
                               ((col * 256 + koff) ^ ((col & 7) << 4)));
            acc[nt] = __builtin_amdgcn_mfma_f32_16x16x32_bf16(a, bb, acc[nt], 0, 0, 0);
        }
    }

    // norms: straight from global (L2-resident, reused across tiles)
    const float4 x2r = *(const float4*)(nx + (size_t)b * T_ + gi0 + 16 * w + 4 * hi);
    float y2c[4];
#pragma unroll
    for (int nt = 0; nt < 4; ++nt)
        y2c[nt] = ny[(size_t)b * T_ + gj0 + nt * 16 + l15];
    const float x2v[4] = {x2r.x, x2r.y, x2r.z, x2r.w};

    __syncthreads();                        // all MFMA LDS reads complete
    unsigned short* Ts = (unsigned short*)smem;   // f16 overlay, stride 68
#pragma unroll
    for (int nt = 0; nt < 4; ++nt) {
        const int col = nt * 16 + l15;
#pragma unroll
        for (int r = 0; r < 4; ++r) {
            const int row = 16 * w + hi * 4 + r;
            const float c = sqrtf(fmaxf(x2v[r] + y2c[nt] - 2.f * acc[nt][r], 0.f));
            const _Float16 hv = (_Float16)c;       // RNE
            Ts[row * 68 + col] = *(const unsigned short*)&hv;
        }
    }
    __syncthreads();

    unsigned short* outD = costD + (size_t)bl * (DIAG_N * (size_t)T_);
    const int tbase = gi0 + gj0;
#pragma unroll 4
    for (int g = 0; g < 32; ++g) {
        const int tloc = g * 4 + w;        // 0..127, wave-uniform
        if (tloc <= 126) {                 // uniform branch (guards tile edge)
            const int c0 = tloc > 63 ? tloc - 63 : 0;   // uniform
            const int c1 = tloc < 63 ? tloc : 63;       // uniform
            const int c  = min(c0 + lane, c1);          // clamped: dup stores benign
            outD[(size_t)(tbase + tloc) * T_ + gj0 + c] = Ts[(tloc - c) * 68 + c];
        }
    }
}

// ---------------------------------------------------------------------------
// Kernel 2: anti-diagonal DTW DP. 32-row LDS ring staged by global_load_lds
// with counted vmcnt (never 0 in the loop). Round 9 change: LDS->register
// double-buffer one 8-tick block ahead — ds_read_b128 x8 of block k+1 issue
// before STEP8 of block k, so the ~120cy DS latency (measured as the tick
// floor in round 8: 160cy/tick at VALU ~40) overlaps a full block of VALU.
// Banks ping-pong via a 2-block unrolled body (static names only).
// ---------------------------------------------------------------------------
__global__ __launch_bounds__(64, 1) void dtw_dp_diag(
    const unsigned short* __restrict__ costD, float* __restrict__ out, int b0)
{
    const int bl = blockIdx.x;
    const int L  = threadIdx.x;
    const unsigned short* gbase = costD + (size_t)bl * (DIAG_N * (size_t)T_) + 8 * L;

    __shared__ __align__(16) unsigned short ring[32][T_];   // 32 KB = 4 blocks

    float va0 = BIGV, va1 = BIGV, va2 = BIGV, va3 = BIGV,
          va4 = BIGV, va5 = BIGV, va6 = BIGV, va7 = BIGV;
    float vb0 = BIGV, vb1 = BIGV, vb2 = BIGV, vb3 = BIGV,
          vb4 = BIGV, vb5 = BIGV, vb6 = BIGV, vb7 = BIGV;

    float s2c = (L == 0) ? 0.f : BIGV;

    half8 ca0, ca1, ca2, ca3, ca4, ca5, ca6, ca7;   // cost regs, block A
    half8 cb0, cb1, cb2, cb3, cb4, cb5, cb6, cb7;   // cost regs, block B

#define GLD(row, slot)                                                      \
    __builtin_amdgcn_global_load_lds(                                       \
        (const __attribute__((address_space(1))) void*)(gbase + (size_t)(row) * T_), \
        (__attribute__((address_space(3))) void*)(&ring[slot][0]), 16, 0, 0)

#define GLD8(blk) do {                                                      \
    const int r0_ = (blk) * 8, s0_ = ((blk) & 3) * 8;                       \
    GLD(r0_ + 0, s0_ + 0); GLD(r0_ + 1, s0_ + 1);                           \
    GLD(r0_ + 2, s0_ + 2); GLD(r0_ + 3, s0_ + 3);                           \
    GLD(r0_ + 4, s0_ + 4); GLD(r0_ + 5, s0_ + 5);                           \
    GLD(r0_ + 6, s0_ + 6); GLD(r0_ + 7, s0_ + 7);                           \
} while (0)

#define WAITV(n)                                                            \
    do { asm volatile("s_waitcnt vmcnt(" #n ")" ::: "memory");              \
         __builtin_amdgcn_sched_barrier(0); } while (0)

#define SB __builtin_amdgcn_sched_barrier(0)

#define RL8(BK, blk) do {                                                   \
    const unsigned short* rp_ = &ring[((blk) & 3) * 8][8 * L];              \
    BK##0 = *(const half8*)(rp_ + 0 * T_);                                  \
    BK##1 = *(const half8*)(rp_ + 1 * T_);                                  \
    BK##2 = *(const half8*)(rp_ + 2 * T_);                                  \
    BK##3 = *(const half8*)(rp_ + 3 * T_);                                  \
    BK##4 = *(const half8*)(rp_ + 4 * T_);                                  \
    BK##5 = *(const half8*)(rp_ + 5 * T_);                                  \
    BK##6 = *(const half8*)(rp_ + 6 * T_);                                  \
    BK##7 = *(const half8*)(rp_ + 7 * T_);                                  \
} while (0)

#define STEP_A(hh) do {                                                     \
    const float s1 = wave_shr1(va7, BIGV);                                  \
    const float n0 = (float)hh[0] + fminf(fminf(va0, s1),  s2c);            \
    const float n1 = (float)hh[1] + fminf(fminf(va1, va0), vb0);            \
    const float n2 = (float)hh[2] + fminf(fminf(va2, va1), vb1);            \
    const float n3 = (float)hh[3] + fminf(fminf(va3, va2), vb2);            \
    const float n4 = (float)hh[4] + fminf(fminf(va4, va3), vb3);            \
    const float n5 = (float)hh[5] + fminf(fminf(va5, va4), vb4);            \
    const float n6 = (float)hh[6] + fminf(fminf(va6, va5), vb5);            \
    const float n7 = (float)hh[7] + fminf(fminf(va7, va6), vb6);            \
    s2c = s1;                                                               \
    vb0 = n0; vb1 = n1; vb2 = n2; vb3 = n3;                                 \
    vb4 = n4; vb5 = n5; vb6 = n6; vb7 = n7;                                 \
} while (0)

#define STEP_B(hh) do {                                                     \
    const float s1 = wave_shr1(vb7, BIGV);                                  \
    const float n0 = (float)hh[0] + fminf(fminf(vb0, s1),  s2c);            \
    const float n1 = (float)hh[1] + fminf(fminf(vb1, vb0), va0);            \
    const float n2 = (float)hh[2] + fminf(fminf(vb2, vb1), va1);            \
    const float n3 = (float)hh[3] + fminf(fminf(vb3, vb2), va2);            \
    const float n4 = (float)hh[4] + fminf(fminf(vb4, vb3), va3);            \
    const float n5 = (float)hh[5] + fminf(fminf(vb5, vb4), va4);            \
    const float n6 = (float)hh[6] + fminf(fminf(vb6, vb5), va5);            \
    const float n7 = (float)hh[7] + fminf(fminf(vb7, vb6), va6);            \
    s2c = s1;                                                               \
    va0 = n0; va1 = n1; va2 = n2; va3 = n3;                                 \
    va4 = n4; va5 = n5; va6 = n6; va7 = n7;                                 \
} while (0)

#define STEP8X(BK)                                                          \
    STEP_A(BK##0); STEP_B(BK##1); STEP_A(BK##2); STEP_B(BK##3);             \
    STEP_A(BK##4); STEP_B(BK##5); STEP_A(BK##6); STEP_B(BK##7)

    // prologue: blocks 0..3 (rows 0..31) in flight
#pragma unroll
    for (int r = 0; r < 32; ++r) GLD(r, r);
    WAITV(24);                 // block 0 landed
    RL8(ca, 0); SB;

    int k = 0;
#pragma unroll 1
    for (int it = 0; it < 62; ++it) {      // blocks 0..123 stepped
        WAITV(16);                         // blocks <= k+1 landed
        RL8(cb, k + 1); SB;
        STEP8X(ca); SB;
        GLD8(k + 4); SB;
        WAITV(16);                         // blocks <= k+2 landed
        RL8(ca, k + 2); SB;
        STEP8X(cb); SB;
        GLD8(k + 5); SB;
        k += 2;
    }
    // k = 124; ca = block 124; in flight: blocks 125, 126, 127
    WAITV(16); RL8(cb, 125); SB; STEP8X(ca); SB;    // block 124
    WAITV(8);  RL8(ca, 126); SB; STEP8X(cb); SB;    // block 125
    WAITV(0);  RL8(cb, 127); SB; STEP8X(ca); SB;    // block 126
    // block 127: ticks 1016..1022 (7 steps; row 1023 junk, never stepped)
    STEP_A(cb0); STEP_B(cb1); STEP_A(cb2); STEP_B(cb3);
    STEP_A(cb4); STEP_B(cb5); STEP_A(cb6);

    if (L == 63) out[b0 + bl] = vb7;       // dp[511][511]
#undef GLD
#undef GLD8
#undef WAITV
#undef SB
#undef RL8
#undef STEP_A
#undef STEP_B
#undef STEP8X
}

// ---------------------------------------------------------------------------
extern "C" void kernel_launch(void* const* d_in, const int* in_sizes, int n_in,
                              void* d_out, int out_size, void* d_ws, size_t ws_size,
                              hipStream_t stream)
{
    const float* x = (const float*)d_in[0];
    const float* y = (const float*)d_in[1];
    float* out = (float*)d_out;

    unsigned short* xt = (unsigned short*)d_ws;
    unsigned short* yt = xt + (size_t)B_ * T_ * F_;
    float* nx = (float*)(yt + (size_t)B_ * T_ * F_);
    float* ny = nx + (size_t)B_ * T_;
    unsigned short* costD = (unsigned short*)(ny + (size_t)B_ * T_);
    const size_t head = (size_t)((char*)costD - (char*)d_ws);

    const size_t perb = (size_t)DIAG_N * T_ * sizeof(unsigned short); // 1 MiB/batch
    int Bg = 8;
    for (int g = 128; g >= 8; g >>= 1)
        if (ws_size >= head + perb * (size_t)g) { Bg = g; break; }

    hipLaunchKernelGGL(dtw_prep_kernel, dim3(T_ / 64, B_, 2), dim3(256), 0, stream,
                       x, y, xt, yt, nx, ny);

    for (int b0 = 0; b0 < B_; b0 += Bg) {
        dim3 gc(T_ / TS, T_ / TS, Bg);
        hipLaunchKernelGGL(dtw_cost_kernel, gc, dim3(256), 0, stream,
                           xt, yt, nx, ny, costD, b0);
        hipLaunchKernelGGL(dtw_dp_diag, dim3(Bg), dim3(64), 0, stream,
                           costD, out, b0);
    }
}